// Round 10
// baseline (1908.817 us; speedup 1.0000x reference)
//
#include <hip/hip_runtime.h>
#include <cstdint>
#include <cstddef>

// ---------------------------------------------------------------------------
// Seq2Seq bi-GRU encoder (T=512,B=512,D=64,H=128,L=2) + 24-step GRU decoder.
// R18. R17's sched_barrier pin on k_dec REVERTED (+34us regression: loads
// were already batched; pin blocked load/MFMA interleave). Base = R16 (1750).
// One targeted change: split the h-part same-accumulator MFMA chains 4-deep
// -> 2+2 in BOTH scans (scan1 aH -> aHa+aHb; scan0d aRZh/aNh -> two halves),
// merged at gate time. The serial path per step is barrier -> ds_read ->
// h-MFMA chain -> gates -> write; chain dep latency is ~4x40cy of it.
// Everything else VERBATIM R16. Model note: per-SIMD MFMA issue is ~16cy/
// instr -> 36 MFMA x 2 waves = 1152cy/step mandatory pipe time on the 64
// active CUs (matches MfmaUtil 9.1% x 4) -- scan1 is within ~30% of that
// structural floor; this round trims the reducible dep-latency slice.
// ---------------------------------------------------------------------------

typedef __attribute__((ext_vector_type(8))) short short8_t;
typedef __attribute__((ext_vector_type(4))) short short4_t;
typedef __attribute__((ext_vector_type(4))) float f32x4_t;

#define MFMA16(a, b, c) __builtin_amdgcn_mfma_f32_16x16x32_bf16((a), (b), (c), 0, 0, 0)

// raw barrier: LDS flush only; vmem (global loads/stores) stay in flight
#define BAR_LDS() asm volatile("s_waitcnt lgkmcnt(0)\n\ts_barrier" ::: "memory")

static __device__ __forceinline__ float bf2f(unsigned short u) {
  unsigned int v = ((unsigned int)u) << 16;
  return __builtin_bit_cast(float, v);
}
static __device__ __forceinline__ unsigned short f2bf(float f) {
  unsigned int x = __builtin_bit_cast(unsigned int, f);
  x += 0x7fffu + ((x >> 16) & 1u);   // round-to-nearest-even
  return (unsigned short)(x >> 16);
}
static __device__ __forceinline__ short8_t ld8(const unsigned short* p) {
  return *reinterpret_cast<const short8_t*>(p);
}
static __device__ __forceinline__ f32x4_t ldf4(const float* p) {
  return *reinterpret_cast<const f32x4_t*>(p);
}
static __device__ __forceinline__ short8_t cvt8f(const float* p) {
  const f32x4_t* v = reinterpret_cast<const f32x4_t*>(p);
  f32x4_t a = v[0], b = v[1];
  short8_t r;
  r[0] = (short)f2bf(a[0]); r[1] = (short)f2bf(a[1]);
  r[2] = (short)f2bf(a[2]); r[3] = (short)f2bf(a[3]);
  r[4] = (short)f2bf(b[0]); r[5] = (short)f2bf(b[1]);
  r[6] = (short)f2bf(b[2]); r[7] = (short)f2bf(b[3]);
  return r;
}
static __device__ __forceinline__ float frcp(float x) {
  return __builtin_amdgcn_rcpf(x);               // v_rcp_f32, <=1ulp
}
static __device__ __forceinline__ float sigm(float x) {
  return frcp(1.0f + __expf(-x));
}
static __device__ __forceinline__ float tanh_fast(float y) {
  float t = __expf(-2.0f * fabsf(y));
  float r = (1.0f - t) * frcp(1.0f + t);
  return copysignf(r, y);
}

// ------------- prep: cast decoder weights, snapshot x[-1,:,0] ---------------
__global__ void k_prep(const float* __restrict__ x,
                       const float* __restrict__ dWih1, const float* __restrict__ dWhh,
                       unsigned short* __restrict__ bdWih1, unsigned short* __restrict__ bdWhh,
                       float* __restrict__ x0save) {
  const int NW = 24576;   // 196608 elems / 8
  int i = blockIdx.x * blockDim.x + threadIdx.x;
  if (i < NW) {
    *reinterpret_cast<short8_t*>(bdWih1 + (size_t)i * 8) = cvt8f(dWih1 + (size_t)i * 8);
  } else if (i < 2 * NW) {
    int j = i - NW;
    *reinterpret_cast<short8_t*>(bdWhh + (size_t)j * 8) = cvt8f(dWhh + (size_t)j * 8);
  } else if (i < 2 * NW + 512) {
    int b = i - 2 * NW;
    x0save[b] = x[((size_t)511 * 512 + b) * 64];
  }
}

// ------------- copy chunk of x into ws (bwd's private read+overlay buffer) --
__global__ void k_copy(const float* __restrict__ x, float* __restrict__ xc,
                       int b_base, int Bc) {
  size_t i = (size_t)blockIdx.x * blockDim.x + threadIdx.x;
  size_t per = (size_t)Bc * 16;            // float4s per t-slab
  size_t n = (size_t)512 * per;
  if (i >= n) return;
  size_t t = i / per, r = i - t * per;
  const f32x4_t* s =
      reinterpret_cast<const f32x4_t*>(x + ((size_t)t * 512 + b_base) * 64) + r;
  f32x4_t* d = reinterpret_cast<f32x4_t*>(xc + t * per * 4) + r;
  *d = *s;
}

// ---- layer-0 scan, one dir per block (blockIdx.y), gi fused (K=64) ---------
// grid (Bc/16, 2). Block = 16 batch rows, 4 waves; wave w owns h-cols
// [w*32,+32). One-step-ahead gi; h-part accumulator chains split 2+2.
__global__ __launch_bounds__(256, 1) void k_scan0d(
    float* x,                               // (512,512,64) fp32; fwd in+out
    float* xc,                              // (512,Bc,64) fp32 copy; bwd in+out
    const float* __restrict__ Wih,          // enc_Wih0 (2,384,64) fp32
    const float* __restrict__ bih,          // (2,384) layer0
    const float* __restrict__ Whh,          // (2,384,128) layer0
    const float* __restrict__ bhh,          // (2,384) layer0
    float* __restrict__ HS,                 // (4,512,128) fp32
    int b_base, int Bc) {
  int dir = blockIdx.y;
  int bl0 = blockIdx.x * 16;                // chunk-local batch base
  int b0g = b_base + bl0;                   // global batch base
  float* xin = dir ? xc : x;                // private read+overlay buffer
  unsigned short* yout = (unsigned short*)xin;
  int xstr = dir ? Bc : 512;                // row stride in that buffer
  int xb0 = dir ? bl0 : b0g;                // row base in that buffer
  int tid = threadIdx.x, w = tid >> 6, lane = tid & 63, q = lane >> 4, c16 = lane & 15;
  __shared__ unsigned short xl[2][16 * 72];    // x tile bf16 (+8 pad)
  __shared__ unsigned short hl[2][16 * 136];   // h tile bf16 (+8 pad)
  const float* Wi = Wih + (size_t)dir * 384 * 64;
  const float* Wh = Whh + (size_t)dir * 384 * 128;
  const float* bi = bih + dir * 384;
  const float* bh = bhh + dir * 384;

  short8_t fi[6][2], fh[6][4];
  float brz[4], bni[2], bnh[2];
#pragma unroll
  for (int g = 0; g < 3; g++)
#pragma unroll
    for (int cc = 0; cc < 2; cc++) {
      int f = g * 2 + cc;
      int n0 = g * 128 + w * 32 + cc * 16;
#pragma unroll
      for (int kt = 0; kt < 2; kt++)
        fi[f][kt] = cvt8f(Wi + (size_t)(n0 + c16) * 64 + kt * 32 + q * 8);
#pragma unroll
      for (int kt = 0; kt < 4; kt++)
        fh[f][kt] = cvt8f(Wh + (size_t)(n0 + c16) * 128 + kt * 32 + q * 8);
      if (g < 2) brz[f] = bi[n0 + c16] + bh[n0 + c16];
      else { bni[cc] = bi[n0 + c16]; bnh[cc] = bh[n0 + c16]; }
    }

  float h[2][4];
#pragma unroll
  for (int cc = 0; cc < 2; cc++)
#pragma unroll
    for (int rr = 0; rr < 4; rr++) h[cc][rr] = 0.f;
  for (int i = tid; i < 16 * 136; i += 256) hl[0][i] = 0;

  int srow = tid >> 4, sc = tid & 15;          // staging/writeback roles
#pragma unroll
  for (int k = 0; k < 2; k++) {                // stage x tiles for steps 0,1
    int tk = dir ? (511 - k) : k;
    f32x4_t v = ldf4(xin + ((size_t)tk * xstr + xb0 + srow) * 64 + sc * 4);
    unsigned short* dst = &xl[k][srow * 72 + sc * 4];
    dst[0] = f2bf(v[0]); dst[1] = f2bf(v[1]); dst[2] = f2bf(v[2]); dst[3] = f2bf(v[3]);
  }
  f32x4_t pA, pB;                              // prefetch regs (x(s+2) held)
  {                                            // pA <- x(step 2)
    int t2 = dir ? 509 : 2;
    pA = ldf4(xin + ((size_t)t2 * xstr + xb0 + srow) * 64 + sc * 4);
  }
  __syncthreads();                             // prologue: full drain once

  // gx(0) from xl[0] (gx layout: [0..3]=RZ by f, [4..5]=Ni by cc)
  f32x4_t gxA[6], gxB[6];
#pragma unroll
  for (int f = 0; f < 6; f++) gxA[f] = (f32x4_t){0.f, 0.f, 0.f, 0.f};
#pragma unroll
  for (int kt = 0; kt < 2; kt++) {
    short8_t ax = ld8(&xl[0][c16 * 72 + kt * 32 + q * 8]);
#pragma unroll
    for (int f = 0; f < 4; f++) gxA[f] = MFMA16(ax, fi[f][kt], gxA[f]);
#pragma unroll
    for (int cc = 0; cc < 2; cc++) gxA[4 + cc] = MFMA16(ax, fi[4 + cc][kt], gxA[4 + cc]);
  }
  BAR_LDS();                                   // protect xl[0] reads from body(0)'s commit

  auto body = [&](int s, f32x4_t (&gxC)[6], f32x4_t (&gxN)[6],
                  const f32x4_t& xu, f32x4_t& xnl) {
    int cur = s & 1, nxt = cur ^ 1;            // hl slots; xl: rd=nxt, wr=cur
    if (s < 509) {                             // issue load for x(s+3)
      int tn = dir ? (508 - s) : (s + 3);
      xnl = ldf4(xin + ((size_t)tn * xstr + xb0 + srow) * 64 + sc * 4);
    }
    if (s < 510) {                             // commit x(s+2) into xl[cur]
      unsigned short* dst = &xl[cur][srow * 72 + sc * 4];
      dst[0] = f2bf(xu[0]); dst[1] = f2bf(xu[1]); dst[2] = f2bf(xu[2]); dst[3] = f2bf(xu[3]);
    }
    if (s > 0) {                               // Yout for h(s-1), held in hl[cur]
      int tp = dir ? (512 - s) : (s - 1);
      short8_t v = ld8(&hl[cur][srow * 136 + sc * 8]);
      *reinterpret_cast<short8_t*>(
          yout + ((size_t)tp * xstr + xb0 + srow) * 128 + sc * 8) = v;
    }
    // ---- serial h-part (chains split 2+2) ----
    short8_t ah[4];
#pragma unroll
    for (int kt = 0; kt < 4; kt++) ah[kt] = ld8(&hl[cur][c16 * 136 + kt * 32 + q * 8]);
    f32x4_t aRZh[4], aRZh2[4], aNh[2], aNh2[2];
#pragma unroll
    for (int f = 0; f < 4; f++) {
      aRZh[f] = (f32x4_t){0.f, 0.f, 0.f, 0.f};
      aRZh2[f] = (f32x4_t){0.f, 0.f, 0.f, 0.f};
    }
#pragma unroll
    for (int cc = 0; cc < 2; cc++) {
      aNh[cc] = (f32x4_t){0.f, 0.f, 0.f, 0.f};
      aNh2[cc] = (f32x4_t){0.f, 0.f, 0.f, 0.f};
    }
#pragma unroll
    for (int kt = 0; kt < 2; kt++) {
#pragma unroll
      for (int f = 0; f < 4; f++) aRZh[f] = MFMA16(ah[kt], fh[f][kt], aRZh[f]);
#pragma unroll
      for (int cc = 0; cc < 2; cc++) aNh[cc] = MFMA16(ah[kt], fh[4 + cc][kt], aNh[cc]);
    }
#pragma unroll
    for (int kt = 2; kt < 4; kt++) {
#pragma unroll
      for (int f = 0; f < 4; f++) aRZh2[f] = MFMA16(ah[kt], fh[f][kt], aRZh2[f]);
#pragma unroll
      for (int cc = 0; cc < 2; cc++) aNh2[cc] = MFMA16(ah[kt], fh[4 + cc][kt], aNh2[cc]);
    }
    // ---- off-path: gx(s+1) from xl[nxt] ----
    if (s < 511) {
#pragma unroll
      for (int f = 0; f < 6; f++) gxN[f] = (f32x4_t){0.f, 0.f, 0.f, 0.f};
#pragma unroll
      for (int kt = 0; kt < 2; kt++) {
        short8_t ax = ld8(&xl[nxt][c16 * 72 + kt * 32 + q * 8]);
#pragma unroll
        for (int f = 0; f < 4; f++) gxN[f] = MFMA16(ax, fi[f][kt], gxN[f]);
#pragma unroll
        for (int cc = 0; cc < 2; cc++) gxN[4 + cc] = MFMA16(ax, fi[4 + cc][kt], gxN[4 + cc]);
      }
    }
    // ---- gates (use gx(s) = gxC) ----
#pragma unroll
    for (int cc = 0; cc < 2; cc++)
#pragma unroll
      for (int rr = 0; rr < 4; rr++) {
        float r = sigm(gxC[cc][rr] + (aRZh[cc][rr] + aRZh2[cc][rr]) + brz[cc]);
        float z = sigm(gxC[2 + cc][rr] + (aRZh[2 + cc][rr] + aRZh2[2 + cc][rr]) + brz[2 + cc]);
        float n = tanh_fast(gxC[4 + cc][rr] + bni[cc] +
                            r * ((aNh[cc][rr] + aNh2[cc][rr]) + bnh[cc]));
        float hn = n + z * (h[cc][rr] - n);
        h[cc][rr] = hn;
        hl[nxt][(q * 4 + rr) * 136 + w * 32 + c16 + cc * 16] = f2bf(hn);
      }
    BAR_LDS();
  };

  for (int s2 = 0; s2 < 256; s2++) {
    body(2 * s2, gxA, gxB, pA, pB);
    body(2 * s2 + 1, gxB, gxA, pB, pA);
  }
  {                                            // final Yout row (step 511's h in hl[0])
    int tp = dir ? 0 : 511;
    short8_t v = ld8(&hl[0][srow * 136 + sc * 8]);
    *reinterpret_cast<short8_t*>(
        yout + ((size_t)tp * xstr + xb0 + srow) * 128 + sc * 8) = v;
  }
#pragma unroll
  for (int cc = 0; cc < 2; cc++)
#pragma unroll
    for (int rr = 0; rr < 4; rr++)
      HS[((size_t)dir * 512 + b0g + q * 4 + rr) * 128 + w * 32 + c16 + cc * 16] = h[cc][rr];
}

// ---- layer-1 scan, gi fused (K=256 = [OutF||OutB]), both dirs --------------
// grid (Bc/16, 2). Block = 512 thr (8 waves); wave w owns h-cols [w*16,+16).
// One-step-ahead gi; serial h-part chains split 2+2 (aHa + aHb).
__global__ __launch_bounds__(512, 1) void k_scan1(
    const unsigned short* __restrict__ OutF,  // x overlay
    const unsigned short* __restrict__ OutB,  // xc overlay
    const float* __restrict__ Wih1,           // enc_Wih1 (2,384,256) fp32
    const float* __restrict__ bih1,           // (2,384) layer1
    const float* __restrict__ Whh1,           // (2,384,128) layer1
    const float* __restrict__ bhh1,           // (2,384) layer1
    float* __restrict__ HS,
    int b_base, int Bc) {
  int dir = blockIdx.y;
  int b0l = blockIdx.x * 16;
  int tid = threadIdx.x, w = tid >> 6, lane = tid & 63, q = lane >> 4, c16 = lane & 15;
  __shared__ unsigned short il[2][16 * 264];   // input tile (256 + 8 pad)
  __shared__ unsigned short hl[2][16 * 136];
  const float* Wi = Wih1 + (size_t)dir * 384 * 256;
  const float* Wh = Whh1 + (size_t)dir * 384 * 128;
  const float* bi = bih1 + dir * 384;
  const float* bh = bhh1 + dir * 384;

  short8_t fi[3][8], fh[3][4];
  float brz[2], bni, bnh;
#pragma unroll
  for (int g = 0; g < 3; g++) {
    int n0 = g * 128 + w * 16;
#pragma unroll
    for (int kt = 0; kt < 8; kt++)
      fi[g][kt] = cvt8f(Wi + (size_t)(n0 + c16) * 256 + kt * 32 + q * 8);
#pragma unroll
    for (int kt = 0; kt < 4; kt++)
      fh[g][kt] = cvt8f(Wh + (size_t)(n0 + c16) * 128 + kt * 32 + q * 8);
    if (g < 2) brz[g] = bi[n0 + c16] + bh[n0 + c16];
    else { bni = bi[n0 + c16]; bnh = bh[n0 + c16]; }
  }

  float h[4] = {0.f, 0.f, 0.f, 0.f};
  for (int i = tid; i < 16 * 136; i += 512) hl[0][i] = 0;

  int srow = tid >> 5, sc = tid & 31;          // staging: 16 rows x 32 col-chunks
#pragma unroll
  for (int k = 0; k < 2; k++) {                // stage il for steps 0,1
    int tk = dir ? (511 - k) : k;
    short8_t v = (sc < 16)
        ? ld8(OutF + ((size_t)tk * 512 + b_base + b0l + srow) * 128 + sc * 8)
        : ld8(OutB + ((size_t)tk * Bc + b0l + srow) * 128 + (sc - 16) * 8);
    *reinterpret_cast<short8_t*>(&il[k][srow * 264 + sc * 8]) = v;
  }
  short8_t ivA, ivB;                           // prefetch regs (il(s+2) held)
  {                                            // ivA <- il(step 2)
    int t2 = dir ? 509 : 2;
    ivA = (sc < 16)
        ? ld8(OutF + ((size_t)t2 * 512 + b_base + b0l + srow) * 128 + sc * 8)
        : ld8(OutB + ((size_t)t2 * Bc + b0l + srow) * 128 + (sc - 16) * 8);
  }
  __syncthreads();                             // prologue: full drain once

  // gi(0) from il[0] (single 8-deep chain per g — R14 arithmetic)
  f32x4_t giA[3], giB[3];
#pragma unroll
  for (int g = 0; g < 3; g++) giA[g] = (f32x4_t){0.f, 0.f, 0.f, 0.f};
#pragma unroll
  for (int kt = 0; kt < 8; kt++) {
    short8_t a = ld8(&il[0][c16 * 264 + kt * 32 + q * 8]);
#pragma unroll
    for (int g = 0; g < 3; g++) giA[g] = MFMA16(a, fi[g][kt], giA[g]);
  }
  BAR_LDS();                                   // protect il[0] reads from body(0)'s commit

  auto body = [&](int s, f32x4_t (&giC)[3], f32x4_t (&giN)[3],
                  const short8_t& iu, short8_t& inl) {
    int cur = s & 1, nxt = cur ^ 1;            // hl slots; il: rd=nxt, wr=cur
    if (s < 509) {                             // issue load for il(s+3)
      int tn = dir ? (508 - s) : (s + 3);
      inl = (sc < 16)
          ? ld8(OutF + ((size_t)tn * 512 + b_base + b0l + srow) * 128 + sc * 8)
          : ld8(OutB + ((size_t)tn * Bc + b0l + srow) * 128 + (sc - 16) * 8);
    }
    if (s < 510)                               // commit il(s+2) into il[cur]
      *reinterpret_cast<short8_t*>(&il[cur][srow * 264 + sc * 8]) = iu;
    // ---- serial h-part (chains split 2+2) ----
    f32x4_t aHa[3], aHb[3];
#pragma unroll
    for (int g = 0; g < 3; g++) {
      aHa[g] = (f32x4_t){0.f, 0.f, 0.f, 0.f};
      aHb[g] = (f32x4_t){0.f, 0.f, 0.f, 0.f};
    }
#pragma unroll
    for (int kt = 0; kt < 2; kt++) {
      short8_t a = ld8(&hl[cur][c16 * 136 + kt * 32 + q * 8]);
#pragma unroll
      for (int g = 0; g < 3; g++) aHa[g] = MFMA16(a, fh[g][kt], aHa[g]);
    }
#pragma unroll
    for (int kt = 2; kt < 4; kt++) {
      short8_t a = ld8(&hl[cur][c16 * 136 + kt * 32 + q * 8]);
#pragma unroll
      for (int g = 0; g < 3; g++) aHb[g] = MFMA16(a, fh[g][kt], aHb[g]);
    }
    // ---- off-path: gi(s+1) from il[nxt] ----
    if (s < 511) {
#pragma unroll
      for (int g = 0; g < 3; g++) giN[g] = (f32x4_t){0.f, 0.f, 0.f, 0.f};
#pragma unroll
      for (int kt = 0; kt < 8; kt++) {
        short8_t a = ld8(&il[nxt][c16 * 264 + kt * 32 + q * 8]);
#pragma unroll
        for (int g = 0; g < 3; g++) giN[g] = MFMA16(a, fi[g][kt], giN[g]);
      }
    }
    // ---- gates (use gi(s) = giC) ----
#pragma unroll
    for (int rr = 0; rr < 4; rr++) {
      float r = sigm(giC[0][rr] + (aHa[0][rr] + aHb[0][rr]) + brz[0]);
      float z = sigm(giC[1][rr] + (aHa[1][rr] + aHb[1][rr]) + brz[1]);
      float n = tanh_fast(giC[2][rr] + bni + r * ((aHa[2][rr] + aHb[2][rr]) + bnh));
      float hn = n + z * (h[rr] - n);
      h[rr] = hn;
      hl[nxt][(q * 4 + rr) * 136 + w * 16 + c16] = f2bf(hn);
    }
    BAR_LDS();
  };

  for (int s2 = 0; s2 < 256; s2++) {
    body(2 * s2, giA, giB, ivA, ivB);
    body(2 * s2 + 1, giB, giA, ivB, ivA);
  }
#pragma unroll
  for (int rr = 0; rr < 4; rr++)
    HS[((size_t)(2 + dir) * 512 + b_base + b0l + q * 4 + rr) * 128 + w * 16 + c16] = h[rr];
}

// ------------------------------- decoder (R16, verified; SBAR reverted) -----
// d-cells split across wave groups. 512 thr = 8 waves; d = w>>2, w4 = w&3
// owns cols [w4*32, +32) of its d. Load batches <=24 regs, one live at a
// time. MFMA order per accumulator preserved.
__global__ __launch_bounds__(512, 1) void k_dec(
    const float* __restrict__ x0save,        // (512)
    const float* __restrict__ HS,            // (4,512,128) = [l0f,l0b,l1f,l1b]
    const unsigned short* __restrict__ Whh,  // dec (2,2,384,128) bf16
    const unsigned short* __restrict__ Wih1, // dec (2,384,256) bf16
    const float* __restrict__ Wih0,          // dec (2,384,1) fp32
    const float* __restrict__ bih,           // (2,2,384)
    const float* __restrict__ bhh,           // (2,2,384)
    const float* __restrict__ fc_w,          // (256) fp32
    const float* __restrict__ fcb,           // (1)
    float* __restrict__ out) {               // (24,512)
  int b0 = blockIdx.x * 16;
  int tid = threadIdx.x, w = tid >> 6, lane = tid & 63, q = lane >> 4, c16 = lane & 15;
  int d = w >> 2, w4 = w & 3;
  __shared__ unsigned short hc0[16 * 264];
  __shared__ unsigned short hc1[16 * 264];
  __shared__ float x0s[16];
  __shared__ float fcwf[256];
  int jj = w4 * 32 + c16;  // h-column within this d (biases, LDS addressing)
  int jw = w4 * 32;        // wave column base (MFMA B-frag row bases)

  const unsigned short* Wd0 = Whh + (size_t)d * 384 * 128;        // layer0 own d
  const unsigned short* Wh1 = Whh + (size_t)(2 + d) * 384 * 128;  // layer1 own d
  const unsigned short* Wi1 = Wih1 + (size_t)d * 384 * 256;

  float hs[2][2][4];   // [layer][cc][rr] for own d
#pragma unroll
  for (int l = 0; l < 2; l++)
#pragma unroll
    for (int cc = 0; cc < 2; cc++)
#pragma unroll
      for (int rr = 0; rr < 4; rr++) {
        int row = q * 4 + rr, j = jj + cc * 16;
        int cell = l * 2 + d;
        float v = HS[((size_t)cell * 512 + b0 + row) * 128 + j];
        hs[l][cc][rr] = v;
        unsigned short bv = f2bf(v);
        unsigned short* tile = l ? hc1 : hc0;
        tile[row * 264 + d * 128 + j] = bv;
      }
  if (tid < 16) x0s[tid] = x0save[b0 + tid];
  if (tid < 256) fcwf[tid] = fc_w[tid];

  float w0c[2][3], bi0[2][3], bh0[2][3], bi1[2][3], bh1[2][3];
#pragma unroll
  for (int cc = 0; cc < 2; cc++)
#pragma unroll
    for (int g = 0; g < 3; g++) {
      int col = g * 128 + jj + cc * 16;
      w0c[cc][g] = Wih0[d * 384 + col];
      bi0[cc][g] = bih[d * 384 + col];
      bh0[cc][g] = bhh[d * 384 + col];
      bi1[cc][g] = bih[(2 + d) * 384 + col];
      bh1[cc][g] = bhh[(2 + d) * 384 + col];
    }
  __syncthreads();

  for (int st = 0; st < 24; st++) {
    // ---- layer 0 (input = scalar x0), own d only ----
    float hn0[2][4];
    {
      short8_t a0[4];
#pragma unroll
      for (int kt = 0; kt < 4; kt++)
        a0[kt] = ld8(&hc0[c16 * 264 + d * 128 + kt * 32 + q * 8]);
      short8_t w0[24];                         // batch 24 loads
#pragma unroll
      for (int kt = 0; kt < 4; kt++)
#pragma unroll
        for (int g = 0; g < 3; g++)
#pragma unroll
          for (int cc = 0; cc < 2; cc++) {
            int n0 = g * 128 + jw + cc * 16;
            w0[kt * 6 + g * 2 + cc] =
                ld8(Wd0 + (size_t)(n0 + c16) * 128 + kt * 32 + q * 8);
          }
      f32x4_t acc[6];
#pragma unroll
      for (int f = 0; f < 6; f++) acc[f] = (f32x4_t){0.f, 0.f, 0.f, 0.f};
#pragma unroll
      for (int kt = 0; kt < 4; kt++)
#pragma unroll
        for (int g = 0; g < 3; g++)
#pragma unroll
          for (int cc = 0; cc < 2; cc++) {
            int f = g * 2 + cc;
            acc[f] = MFMA16(a0[kt], w0[kt * 6 + g * 2 + cc], acc[f]);
          }
#pragma unroll
      for (int cc = 0; cc < 2; cc++)
#pragma unroll
        for (int rr = 0; rr < 4; rr++) {
          float xin = x0s[q * 4 + rr];
          float r = sigm(xin * w0c[cc][0] + bi0[cc][0] + acc[cc][rr] + bh0[cc][0]);
          float z = sigm(xin * w0c[cc][1] + bi0[cc][1] + acc[2 + cc][rr] + bh0[cc][1]);
          float n = tanh_fast(xin * w0c[cc][2] + bi0[cc][2] +
                              r * (acc[4 + cc][rr] + bh0[cc][2]));
          float hv = n + z * (hs[0][cc][rr] - n);
          hn0[cc][rr] = hv;
          hs[0][cc][rr] = hv;
        }
    }
    __syncthreads();
#pragma unroll
    for (int cc = 0; cc < 2; cc++)
#pragma unroll
      for (int rr = 0; rr < 4; rr++)
        hc0[(q * 4 + rr) * 264 + d * 128 + jj + cc * 16] = f2bf(hn0[cc][rr]);
    __syncthreads();

    // ---- layer 1 (input = hc0 concat), own d only ----
    float hn1[2][4];
    {
      short8_t ai[8];
#pragma unroll
      for (int kt = 0; kt < 8; kt++) ai[kt] = ld8(&hc0[c16 * 264 + kt * 32 + q * 8]);
      short8_t ah[4];
#pragma unroll
      for (int kt = 0; kt < 4; kt++)
        ah[kt] = ld8(&hc1[c16 * 264 + d * 128 + kt * 32 + q * 8]);
      f32x4_t aRZ[4], aNi[2], aNh[2];
#pragma unroll
      for (int f = 0; f < 4; f++) aRZ[f] = (f32x4_t){0.f, 0.f, 0.f, 0.f};
#pragma unroll
      for (int cc = 0; cc < 2; cc++) {
        aNi[cc] = (f32x4_t){0.f, 0.f, 0.f, 0.f};
        aNh[cc] = (f32x4_t){0.f, 0.f, 0.f, 0.f};
      }
      {                                        // batch A: Wi kt 0..3
        short8_t wA[24];
#pragma unroll
        for (int kt = 0; kt < 4; kt++) {
#pragma unroll
          for (int f = 0; f < 4; f++) {
            int n0 = (f >> 1) * 128 + jw + (f & 1) * 16;
            wA[kt * 6 + f] = ld8(Wi1 + (size_t)(n0 + c16) * 256 + kt * 32 + q * 8);
          }
#pragma unroll
          for (int cc = 0; cc < 2; cc++) {
            int n0 = 256 + jw + cc * 16;
            wA[kt * 6 + 4 + cc] = ld8(Wi1 + (size_t)(n0 + c16) * 256 + kt * 32 + q * 8);
          }
        }
#pragma unroll
        for (int kt = 0; kt < 4; kt++) {
#pragma unroll
          for (int f = 0; f < 4; f++) aRZ[f] = MFMA16(ai[kt], wA[kt * 6 + f], aRZ[f]);
#pragma unroll
          for (int cc = 0; cc < 2; cc++) aNi[cc] = MFMA16(ai[kt], wA[kt * 6 + 4 + cc], aNi[cc]);
        }
      }
      {                                        // batch B: Wi kt 4..7
        short8_t wB[24];
#pragma unroll
        for (int kt = 0; kt < 4; kt++) {
#pragma unroll
          for (int f = 0; f < 4; f++) {
            int n0 = (f >> 1) * 128 + jw + (f & 1) * 16;
            wB[kt * 6 + f] = ld8(Wi1 + (size_t)(n0 + c16) * 256 + (kt + 4) * 32 + q * 8);
          }
#pragma unroll
          for (int cc = 0; cc < 2; cc++) {
            int n0 = 256 + jw + cc * 16;
            wB[kt * 6 + 4 + cc] = ld8(Wi1 + (size_t)(n0 + c16) * 256 + (kt + 4) * 32 + q * 8);
          }
        }
#pragma unroll
        for (int kt = 0; kt < 4; kt++) {
#pragma unroll
          for (int f = 0; f < 4; f++) aRZ[f] = MFMA16(ai[4 + kt], wB[kt * 6 + f], aRZ[f]);
#pragma unroll
          for (int cc = 0; cc < 2; cc++) aNi[cc] = MFMA16(ai[4 + kt], wB[kt * 6 + 4 + cc], aNi[cc]);
        }
      }
      {                                        // batch H: Wh kt 0..3
        short8_t wH[24];
#pragma unroll
        for (int kt = 0; kt < 4; kt++) {
#pragma unroll
          for (int f = 0; f < 4; f++) {
            int n0 = (f >> 1) * 128 + jw + (f & 1) * 16;
            wH[kt * 6 + f] = ld8(Wh1 + (size_t)(n0 + c16) * 128 + kt * 32 + q * 8);
          }
#pragma unroll
          for (int cc = 0; cc < 2; cc++) {
            int n0 = 256 + jw + cc * 16;
            wH[kt * 6 + 4 + cc] = ld8(Wh1 + (size_t)(n0 + c16) * 128 + kt * 32 + q * 8);
          }
        }
#pragma unroll
        for (int kt = 0; kt < 4; kt++) {
#pragma unroll
          for (int f = 0; f < 4; f++) aRZ[f] = MFMA16(ah[kt], wH[kt * 6 + f], aRZ[f]);
#pragma unroll
          for (int cc = 0; cc < 2; cc++) aNh[cc] = MFMA16(ah[kt], wH[kt * 6 + 4 + cc], aNh[cc]);
        }
      }
#pragma unroll
      for (int cc = 0; cc < 2; cc++)
#pragma unroll
        for (int rr = 0; rr < 4; rr++) {
          float r = sigm(aRZ[cc][rr] + bi1[cc][0] + bh1[cc][0]);
          float z = sigm(aRZ[2 + cc][rr] + bi1[cc][1] + bh1[cc][1]);
          float n = tanh_fast(aNi[cc][rr] + bi1[cc][2] + r * (aNh[cc][rr] + bh1[cc][2]));
          float hv = n + z * (hs[1][cc][rr] - n);
          hn1[cc][rr] = hv;
          hs[1][cc][rr] = hv;
        }
    }
    __syncthreads();
#pragma unroll
    for (int cc = 0; cc < 2; cc++)
#pragma unroll
      for (int rr = 0; rr < 4; rr++)
        hc1[(q * 4 + rr) * 264 + d * 128 + jj + cc * 16] = f2bf(hn1[cc][rr]);
    __syncthreads();

    // ---- fc -> pred, feed back (wave 0 only) ----
    if (w == 0) {
      float s = 0.f;
#pragma unroll
      for (int i = 0; i < 8; i++) {
        short8_t hv = ld8(&hc1[c16 * 264 + q * 64 + i * 8]);
#pragma unroll
        for (int e = 0; e < 8; e++)
          s += bf2f((unsigned short)hv[e]) * fcwf[q * 64 + i * 8 + e];
      }
      s += __shfl_xor(s, 16);
      s += __shfl_xor(s, 32);
      if (q == 0) {
        float pred = s + fcb[0];
        x0s[c16] = pred;
        out[(size_t)st * 512 + b0 + c16] = pred;
      }
    }
    __syncthreads();
  }
}

// ---------------------------------------------------------------------------
extern "C" void kernel_launch(void* const* d_in, const int* in_sizes, int n_in,
                              void* d_out, int out_size, void* d_ws, size_t ws_size,
                              hipStream_t stream) {
  const float* x     = (const float*)d_in[0];
  const float* eWih0 = (const float*)d_in[1];
  const float* eWih1 = (const float*)d_in[2];
  const float* eWhh  = (const float*)d_in[3];
  const float* ebih  = (const float*)d_in[4];
  const float* ebhh  = (const float*)d_in[5];
  const float* dWih0 = (const float*)d_in[6];
  const float* dWih1 = (const float*)d_in[7];
  const float* dWhh  = (const float*)d_in[8];
  const float* dbih  = (const float*)d_in[9];
  const float* dbhh  = (const float*)d_in[10];
  const float* fc_w  = (const float*)d_in[11];
  const float* fc_b  = (const float*)d_in[12];
  float* out = (float*)d_out;
  (void)in_sizes; (void)n_in; (void)out_size;

  // ---- ws ladder: xc = Bc*131072 bytes (512 t x Bc rows x 64 fp32) --------
  // Bc=512 total 68.95MB == previously-passing budget; else Bc=256 (35.4MB)
  const size_t fixedB = 2048 + 1048576 + 393216 + 393216 + 4096;
  int Bc = 256;
  if (fixedB + (size_t)512 * 131072 <= ws_size) Bc = 512;

  char* ws = (char*)d_ws;
  size_t off = 0;
  auto alloc = [&](size_t bytes) -> char* {
    off = (off + 255) & ~(size_t)255;
    char* p = ws + off;
    off += bytes;
    return p;
  };
  float* x0save          = (float*)alloc(2048);
  float* HS              = (float*)alloc(1048576);
  unsigned short* bdWih1 = (unsigned short*)alloc(393216);   // 196608 elems
  unsigned short* bdWhh  = (unsigned short*)alloc(393216);   // 196608 elems
  float* xc              = (float*)alloc((size_t)Bc * 131072);

  k_prep<<<194, 256, 0, stream>>>(x, dWih1, dWhh, bdWih1, bdWhh, x0save);

  float* xm = (float*)d_in[0];   // mutable view: fwd overlay target
  const float* Whh1 = eWhh + (size_t)2 * 384 * 128;
  int nchunks = 512 / Bc;
  for (int c = 0; c < nchunks; c++) {
    int b_base = c * Bc;
    int ncopy = (512 * Bc * 16 + 255) / 256;
    k_copy<<<ncopy, 256, 0, stream>>>(x, xc, b_base, Bc);
    k_scan0d<<<dim3(Bc / 16, 2), 256, 0, stream>>>(xm, xc, eWih0, ebih, eWhh, ebhh,
                                                   HS, b_base, Bc);
    k_scan1<<<dim3(Bc / 16, 2), 512, 0, stream>>>((const unsigned short*)xm,
                                                  (const unsigned short*)xc,
                                                  eWih1, ebih + 768, Whh1,
                                                  ebhh + 768, HS, b_base, Bc);
  }
  k_dec<<<dim3(32), 512, 0, stream>>>(x0save, HS, bdWhh, bdWih1, dWih0, dbih, dbhh,
                                      fc_w, fc_b, out);
}

// Round 11
// 1755.675 us; speedup vs baseline: 1.0872x; 1.0872x over previous
//
#include <hip/hip_runtime.h>
#include <cstdint>
#include <cstddef>

// ---------------------------------------------------------------------------
// Seq2Seq bi-GRU encoder (T=512,B=512,D=64,H=128,L=2) + 24-step GRU decoder.
// R19. R18's chain split REVERTED (regressed both scans: scan0d VGPR 164->196
// cost ~210us; serial h-MFMA chain was NOT the critical path). Scans = R16
// verbatim (best: scan1 679, scan0d ~500, one-step-ahead gi).
// k_dec: extend the ONE empirically-proven dec lever (R13 wave-split, -77us)
// further: 1024-thr blocks, 16 waves (4/SIMD). wave = (d = w>>3, w8 = w&7)
// owns 16 cols of its dir (half of R16's 32). Per-wave MFMAs/loads halve,
// TLP doubles -- dec is latency-bound (step ~45kcy vs ~6kcy bottom-up floor).
// VGPR cap 128 (launch_bounds 1024): 2-kt load batches (6 regs), ai loaded
// in two 4-kt halves; peak live ~100 VGPR. Per-accumulator MFMA order
// preserved exactly (kt ascending; aRZ: Wi kt0..7 then Wh kt0..3) ->
// bit-identical. prep/copy/launcher unchanged.
// ---------------------------------------------------------------------------

typedef __attribute__((ext_vector_type(8))) short short8_t;
typedef __attribute__((ext_vector_type(4))) short short4_t;
typedef __attribute__((ext_vector_type(4))) float f32x4_t;

#define MFMA16(a, b, c) __builtin_amdgcn_mfma_f32_16x16x32_bf16((a), (b), (c), 0, 0, 0)

// raw barrier: LDS flush only; vmem (global loads/stores) stay in flight
#define BAR_LDS() asm volatile("s_waitcnt lgkmcnt(0)\n\ts_barrier" ::: "memory")

static __device__ __forceinline__ float bf2f(unsigned short u) {
  unsigned int v = ((unsigned int)u) << 16;
  return __builtin_bit_cast(float, v);
}
static __device__ __forceinline__ unsigned short f2bf(float f) {
  unsigned int x = __builtin_bit_cast(unsigned int, f);
  x += 0x7fffu + ((x >> 16) & 1u);   // round-to-nearest-even
  return (unsigned short)(x >> 16);
}
static __device__ __forceinline__ short8_t ld8(const unsigned short* p) {
  return *reinterpret_cast<const short8_t*>(p);
}
static __device__ __forceinline__ f32x4_t ldf4(const float* p) {
  return *reinterpret_cast<const f32x4_t*>(p);
}
static __device__ __forceinline__ short8_t cvt8f(const float* p) {
  const f32x4_t* v = reinterpret_cast<const f32x4_t*>(p);
  f32x4_t a = v[0], b = v[1];
  short8_t r;
  r[0] = (short)f2bf(a[0]); r[1] = (short)f2bf(a[1]);
  r[2] = (short)f2bf(a[2]); r[3] = (short)f2bf(a[3]);
  r[4] = (short)f2bf(b[0]); r[5] = (short)f2bf(b[1]);
  r[6] = (short)f2bf(b[2]); r[7] = (short)f2bf(b[3]);
  return r;
}
static __device__ __forceinline__ float frcp(float x) {
  return __builtin_amdgcn_rcpf(x);               // v_rcp_f32, <=1ulp
}
static __device__ __forceinline__ float sigm(float x) {
  return frcp(1.0f + __expf(-x));
}
static __device__ __forceinline__ float tanh_fast(float y) {
  float t = __expf(-2.0f * fabsf(y));
  float r = (1.0f - t) * frcp(1.0f + t);
  return copysignf(r, y);
}

// ------------- prep: cast decoder weights, snapshot x[-1,:,0] ---------------
__global__ void k_prep(const float* __restrict__ x,
                       const float* __restrict__ dWih1, const float* __restrict__ dWhh,
                       unsigned short* __restrict__ bdWih1, unsigned short* __restrict__ bdWhh,
                       float* __restrict__ x0save) {
  const int NW = 24576;   // 196608 elems / 8
  int i = blockIdx.x * blockDim.x + threadIdx.x;
  if (i < NW) {
    *reinterpret_cast<short8_t*>(bdWih1 + (size_t)i * 8) = cvt8f(dWih1 + (size_t)i * 8);
  } else if (i < 2 * NW) {
    int j = i - NW;
    *reinterpret_cast<short8_t*>(bdWhh + (size_t)j * 8) = cvt8f(dWhh + (size_t)j * 8);
  } else if (i < 2 * NW + 512) {
    int b = i - 2 * NW;
    x0save[b] = x[((size_t)511 * 512 + b) * 64];
  }
}

// ------------- copy chunk of x into ws (bwd's private read+overlay buffer) --
__global__ void k_copy(const float* __restrict__ x, float* __restrict__ xc,
                       int b_base, int Bc) {
  size_t i = (size_t)blockIdx.x * blockDim.x + threadIdx.x;
  size_t per = (size_t)Bc * 16;            // float4s per t-slab
  size_t n = (size_t)512 * per;
  if (i >= n) return;
  size_t t = i / per, r = i - t * per;
  const f32x4_t* s =
      reinterpret_cast<const f32x4_t*>(x + ((size_t)t * 512 + b_base) * 64) + r;
  f32x4_t* d = reinterpret_cast<f32x4_t*>(xc + t * per * 4) + r;
  *d = *s;
}

// ---- layer-0 scan, one dir per block (blockIdx.y), gi fused (K=64) ---------
// grid (Bc/16, 2). Block = 16 batch rows, 4 waves; wave w owns h-cols
// [w*32,+32). One-step-ahead gi: step s computes gx(s+1) off-path, gates use
// gx(s) from registers. Serial path = hl round trip + h-MFMAs + gates. (R16)
__global__ __launch_bounds__(256, 1) void k_scan0d(
    float* x,                               // (512,512,64) fp32; fwd in+out
    float* xc,                              // (512,Bc,64) fp32 copy; bwd in+out
    const float* __restrict__ Wih,          // enc_Wih0 (2,384,64) fp32
    const float* __restrict__ bih,          // (2,384) layer0
    const float* __restrict__ Whh,          // (2,384,128) layer0
    const float* __restrict__ bhh,          // (2,384) layer0
    float* __restrict__ HS,                 // (4,512,128) fp32
    int b_base, int Bc) {
  int dir = blockIdx.y;
  int bl0 = blockIdx.x * 16;                // chunk-local batch base
  int b0g = b_base + bl0;                   // global batch base
  float* xin = dir ? xc : x;                // private read+overlay buffer
  unsigned short* yout = (unsigned short*)xin;
  int xstr = dir ? Bc : 512;                // row stride in that buffer
  int xb0 = dir ? bl0 : b0g;                // row base in that buffer
  int tid = threadIdx.x, w = tid >> 6, lane = tid & 63, q = lane >> 4, c16 = lane & 15;
  __shared__ unsigned short xl[2][16 * 72];    // x tile bf16 (+8 pad)
  __shared__ unsigned short hl[2][16 * 136];   // h tile bf16 (+8 pad)
  const float* Wi = Wih + (size_t)dir * 384 * 64;
  const float* Wh = Whh + (size_t)dir * 384 * 128;
  const float* bi = bih + dir * 384;
  const float* bh = bhh + dir * 384;

  short8_t fi[6][2], fh[6][4];
  float brz[4], bni[2], bnh[2];
#pragma unroll
  for (int g = 0; g < 3; g++)
#pragma unroll
    for (int cc = 0; cc < 2; cc++) {
      int f = g * 2 + cc;
      int n0 = g * 128 + w * 32 + cc * 16;
#pragma unroll
      for (int kt = 0; kt < 2; kt++)
        fi[f][kt] = cvt8f(Wi + (size_t)(n0 + c16) * 64 + kt * 32 + q * 8);
#pragma unroll
      for (int kt = 0; kt < 4; kt++)
        fh[f][kt] = cvt8f(Wh + (size_t)(n0 + c16) * 128 + kt * 32 + q * 8);
      if (g < 2) brz[f] = bi[n0 + c16] + bh[n0 + c16];
      else { bni[cc] = bi[n0 + c16]; bnh[cc] = bh[n0 + c16]; }
    }

  float h[2][4];
#pragma unroll
  for (int cc = 0; cc < 2; cc++)
#pragma unroll
    for (int rr = 0; rr < 4; rr++) h[cc][rr] = 0.f;
  for (int i = tid; i < 16 * 136; i += 256) hl[0][i] = 0;

  int srow = tid >> 4, sc = tid & 15;          // staging/writeback roles
#pragma unroll
  for (int k = 0; k < 2; k++) {                // stage x tiles for steps 0,1
    int tk = dir ? (511 - k) : k;
    f32x4_t v = ldf4(xin + ((size_t)tk * xstr + xb0 + srow) * 64 + sc * 4);
    unsigned short* dst = &xl[k][srow * 72 + sc * 4];
    dst[0] = f2bf(v[0]); dst[1] = f2bf(v[1]); dst[2] = f2bf(v[2]); dst[3] = f2bf(v[3]);
  }
  f32x4_t pA, pB;                              // prefetch regs (x(s+2) held)
  {                                            // pA <- x(step 2)
    int t2 = dir ? 509 : 2;
    pA = ldf4(xin + ((size_t)t2 * xstr + xb0 + srow) * 64 + sc * 4);
  }
  __syncthreads();                             // prologue: full drain once

  // gx(0) from xl[0] (gx layout: [0..3]=RZ by f, [4..5]=Ni by cc)
  f32x4_t gxA[6], gxB[6];
#pragma unroll
  for (int f = 0; f < 6; f++) gxA[f] = (f32x4_t){0.f, 0.f, 0.f, 0.f};
#pragma unroll
  for (int kt = 0; kt < 2; kt++) {
    short8_t ax = ld8(&xl[0][c16 * 72 + kt * 32 + q * 8]);
#pragma unroll
    for (int f = 0; f < 4; f++) gxA[f] = MFMA16(ax, fi[f][kt], gxA[f]);
#pragma unroll
    for (int cc = 0; cc < 2; cc++) gxA[4 + cc] = MFMA16(ax, fi[4 + cc][kt], gxA[4 + cc]);
  }
  BAR_LDS();                                   // protect xl[0] reads from body(0)'s commit

  auto body = [&](int s, f32x4_t (&gxC)[6], f32x4_t (&gxN)[6],
                  const f32x4_t& xu, f32x4_t& xnl) {
    int cur = s & 1, nxt = cur ^ 1;            // hl slots; xl: rd=nxt, wr=cur
    if (s < 509) {                             // issue load for x(s+3)
      int tn = dir ? (508 - s) : (s + 3);
      xnl = ldf4(xin + ((size_t)tn * xstr + xb0 + srow) * 64 + sc * 4);
    }
    if (s < 510) {                             // commit x(s+2) into xl[cur]
      unsigned short* dst = &xl[cur][srow * 72 + sc * 4];
      dst[0] = f2bf(xu[0]); dst[1] = f2bf(xu[1]); dst[2] = f2bf(xu[2]); dst[3] = f2bf(xu[3]);
    }
    if (s > 0) {                               // Yout for h(s-1), held in hl[cur]
      int tp = dir ? (512 - s) : (s - 1);
      short8_t v = ld8(&hl[cur][srow * 136 + sc * 8]);
      *reinterpret_cast<short8_t*>(
          yout + ((size_t)tp * xstr + xb0 + srow) * 128 + sc * 8) = v;
    }
    // ---- serial h-part ----
    short8_t ah[4];
#pragma unroll
    for (int kt = 0; kt < 4; kt++) ah[kt] = ld8(&hl[cur][c16 * 136 + kt * 32 + q * 8]);
    f32x4_t aRZh[4], aNh[2];
#pragma unroll
    for (int f = 0; f < 4; f++) aRZh[f] = (f32x4_t){0.f, 0.f, 0.f, 0.f};
#pragma unroll
    for (int cc = 0; cc < 2; cc++) aNh[cc] = (f32x4_t){0.f, 0.f, 0.f, 0.f};
#pragma unroll
    for (int kt = 0; kt < 4; kt++) {
#pragma unroll
      for (int f = 0; f < 4; f++) aRZh[f] = MFMA16(ah[kt], fh[f][kt], aRZh[f]);
#pragma unroll
      for (int cc = 0; cc < 2; cc++) aNh[cc] = MFMA16(ah[kt], fh[4 + cc][kt], aNh[cc]);
    }
    // ---- off-path: gx(s+1) from xl[nxt] ----
    if (s < 511) {
#pragma unroll
      for (int f = 0; f < 6; f++) gxN[f] = (f32x4_t){0.f, 0.f, 0.f, 0.f};
#pragma unroll
      for (int kt = 0; kt < 2; kt++) {
        short8_t ax = ld8(&xl[nxt][c16 * 72 + kt * 32 + q * 8]);
#pragma unroll
        for (int f = 0; f < 4; f++) gxN[f] = MFMA16(ax, fi[f][kt], gxN[f]);
#pragma unroll
        for (int cc = 0; cc < 2; cc++) gxN[4 + cc] = MFMA16(ax, fi[4 + cc][kt], gxN[4 + cc]);
      }
    }
    // ---- gates (use gx(s) = gxC) ----
#pragma unroll
    for (int cc = 0; cc < 2; cc++)
#pragma unroll
      for (int rr = 0; rr < 4; rr++) {
        float r = sigm(gxC[cc][rr] + aRZh[cc][rr] + brz[cc]);
        float z = sigm(gxC[2 + cc][rr] + aRZh[2 + cc][rr] + brz[2 + cc]);
        float n = tanh_fast(gxC[4 + cc][rr] + bni[cc] + r * (aNh[cc][rr] + bnh[cc]));
        float hn = n + z * (h[cc][rr] - n);
        h[cc][rr] = hn;
        hl[nxt][(q * 4 + rr) * 136 + w * 32 + c16 + cc * 16] = f2bf(hn);
      }
    BAR_LDS();
  };

  for (int s2 = 0; s2 < 256; s2++) {
    body(2 * s2, gxA, gxB, pA, pB);
    body(2 * s2 + 1, gxB, gxA, pB, pA);
  }
  {                                            // final Yout row (step 511's h in hl[0])
    int tp = dir ? 0 : 511;
    short8_t v = ld8(&hl[0][srow * 136 + sc * 8]);
    *reinterpret_cast<short8_t*>(
        yout + ((size_t)tp * xstr + xb0 + srow) * 128 + sc * 8) = v;
  }
#pragma unroll
  for (int cc = 0; cc < 2; cc++)
#pragma unroll
    for (int rr = 0; rr < 4; rr++)
      HS[((size_t)dir * 512 + b0g + q * 4 + rr) * 128 + w * 32 + c16 + cc * 16] = h[cc][rr];
}

// ---- layer-1 scan, gi fused (K=256 = [OutF||OutB]), both dirs --------------
// grid (Bc/16, 2). Block = 512 thr (8 waves); wave w owns h-cols [w*16,+16).
// One-step-ahead gi (R16): step s computes gi(s+1) off-path; gates use gi(s).
__global__ __launch_bounds__(512, 1) void k_scan1(
    const unsigned short* __restrict__ OutF,  // x overlay
    const unsigned short* __restrict__ OutB,  // xc overlay
    const float* __restrict__ Wih1,           // enc_Wih1 (2,384,256) fp32
    const float* __restrict__ bih1,           // (2,384) layer1
    const float* __restrict__ Whh1,           // (2,384,128) layer1
    const float* __restrict__ bhh1,           // (2,384) layer1
    float* __restrict__ HS,
    int b_base, int Bc) {
  int dir = blockIdx.y;
  int b0l = blockIdx.x * 16;
  int tid = threadIdx.x, w = tid >> 6, lane = tid & 63, q = lane >> 4, c16 = lane & 15;
  __shared__ unsigned short il[2][16 * 264];   // input tile (256 + 8 pad)
  __shared__ unsigned short hl[2][16 * 136];
  const float* Wi = Wih1 + (size_t)dir * 384 * 256;
  const float* Wh = Whh1 + (size_t)dir * 384 * 128;
  const float* bi = bih1 + dir * 384;
  const float* bh = bhh1 + dir * 384;

  short8_t fi[3][8], fh[3][4];
  float brz[2], bni, bnh;
#pragma unroll
  for (int g = 0; g < 3; g++) {
    int n0 = g * 128 + w * 16;
#pragma unroll
    for (int kt = 0; kt < 8; kt++)
      fi[g][kt] = cvt8f(Wi + (size_t)(n0 + c16) * 256 + kt * 32 + q * 8);
#pragma unroll
    for (int kt = 0; kt < 4; kt++)
      fh[g][kt] = cvt8f(Wh + (size_t)(n0 + c16) * 128 + kt * 32 + q * 8);
    if (g < 2) brz[g] = bi[n0 + c16] + bh[n0 + c16];
    else { bni = bi[n0 + c16]; bnh = bh[n0 + c16]; }
  }

  float h[4] = {0.f, 0.f, 0.f, 0.f};
  for (int i = tid; i < 16 * 136; i += 512) hl[0][i] = 0;

  int srow = tid >> 5, sc = tid & 31;          // staging: 16 rows x 32 col-chunks
#pragma unroll
  for (int k = 0; k < 2; k++) {                // stage il for steps 0,1
    int tk = dir ? (511 - k) : k;
    short8_t v = (sc < 16)
        ? ld8(OutF + ((size_t)tk * 512 + b_base + b0l + srow) * 128 + sc * 8)
        : ld8(OutB + ((size_t)tk * Bc + b0l + srow) * 128 + (sc - 16) * 8);
    *reinterpret_cast<short8_t*>(&il[k][srow * 264 + sc * 8]) = v;
  }
  short8_t ivA, ivB;                           // prefetch regs (il(s+2) held)
  {                                            // ivA <- il(step 2)
    int t2 = dir ? 509 : 2;
    ivA = (sc < 16)
        ? ld8(OutF + ((size_t)t2 * 512 + b_base + b0l + srow) * 128 + sc * 8)
        : ld8(OutB + ((size_t)t2 * Bc + b0l + srow) * 128 + (sc - 16) * 8);
  }
  __syncthreads();                             // prologue: full drain once

  // gi(0) from il[0] (single 8-deep chain per g — R14 arithmetic)
  f32x4_t giA[3], giB[3];
#pragma unroll
  for (int g = 0; g < 3; g++) giA[g] = (f32x4_t){0.f, 0.f, 0.f, 0.f};
#pragma unroll
  for (int kt = 0; kt < 8; kt++) {
    short8_t a = ld8(&il[0][c16 * 264 + kt * 32 + q * 8]);
#pragma unroll
    for (int g = 0; g < 3; g++) giA[g] = MFMA16(a, fi[g][kt], giA[g]);
  }
  BAR_LDS();                                   // protect il[0] reads from body(0)'s commit

  auto body = [&](int s, f32x4_t (&giC)[3], f32x4_t (&giN)[3],
                  const short8_t& iu, short8_t& inl) {
    int cur = s & 1, nxt = cur ^ 1;            // hl slots; il: rd=nxt, wr=cur
    if (s < 509) {                             // issue load for il(s+3)
      int tn = dir ? (508 - s) : (s + 3);
      inl = (sc < 16)
          ? ld8(OutF + ((size_t)tn * 512 + b_base + b0l + srow) * 128 + sc * 8)
          : ld8(OutB + ((size_t)tn * Bc + b0l + srow) * 128 + (sc - 16) * 8);
    }
    if (s < 510)                               // commit il(s+2) into il[cur]
      *reinterpret_cast<short8_t*>(&il[cur][srow * 264 + sc * 8]) = iu;
    // ---- serial h-part ----
    f32x4_t aH[3];
#pragma unroll
    for (int g = 0; g < 3; g++) aH[g] = (f32x4_t){0.f, 0.f, 0.f, 0.f};
#pragma unroll
    for (int kt = 0; kt < 4; kt++) {
      short8_t a = ld8(&hl[cur][c16 * 136 + kt * 32 + q * 8]);
#pragma unroll
      for (int g = 0; g < 3; g++) aH[g] = MFMA16(a, fh[g][kt], aH[g]);
    }
    // ---- off-path: gi(s+1) from il[nxt] ----
    if (s < 511) {
#pragma unroll
      for (int g = 0; g < 3; g++) giN[g] = (f32x4_t){0.f, 0.f, 0.f, 0.f};
#pragma unroll
      for (int kt = 0; kt < 8; kt++) {
        short8_t a = ld8(&il[nxt][c16 * 264 + kt * 32 + q * 8]);
#pragma unroll
        for (int g = 0; g < 3; g++) giN[g] = MFMA16(a, fi[g][kt], giN[g]);
      }
    }
    // ---- gates (use gi(s) = giC) ----
#pragma unroll
    for (int rr = 0; rr < 4; rr++) {
      float r = sigm(giC[0][rr] + aH[0][rr] + brz[0]);
      float z = sigm(giC[1][rr] + aH[1][rr] + brz[1]);
      float n = tanh_fast(giC[2][rr] + bni + r * (aH[2][rr] + bnh));
      float hn = n + z * (h[rr] - n);
      h[rr] = hn;
      hl[nxt][(q * 4 + rr) * 136 + w * 16 + c16] = f2bf(hn);
    }
    BAR_LDS();
  };

  for (int s2 = 0; s2 < 256; s2++) {
    body(2 * s2, giA, giB, ivA, ivB);
    body(2 * s2 + 1, giB, giA, ivB, ivA);
  }
#pragma unroll
  for (int rr = 0; rr < 4; rr++)
    HS[((size_t)(2 + dir) * 512 + b_base + b0l + q * 4 + rr) * 128 + w * 16 + c16] = h[rr];
}

// ------------------------------- decoder (R19: 16 waves, 4/SIMD) ------------
// 1024 thr = 16 waves; wave = (d = w>>3, w8 = w&7) owns cols [w8*16,+16) of
// its d. Per-wave work = half of R16's; TLP 2x. 2-kt load batches; ai in two
// halves (VGPR cap 128). Per-accumulator MFMA order preserved (kt ascending;
// aRZ: Wi kt0..7 then Wh kt0..3) -> bit-identical to R16.
__global__ __launch_bounds__(1024, 1) void k_dec(
    const float* __restrict__ x0save,        // (512)
    const float* __restrict__ HS,            // (4,512,128) = [l0f,l0b,l1f,l1b]
    const unsigned short* __restrict__ Whh,  // dec (2,2,384,128) bf16
    const unsigned short* __restrict__ Wih1, // dec (2,384,256) bf16
    const float* __restrict__ Wih0,          // dec (2,384,1) fp32
    const float* __restrict__ bih,           // (2,2,384)
    const float* __restrict__ bhh,           // (2,2,384)
    const float* __restrict__ fc_w,          // (256) fp32
    const float* __restrict__ fcb,           // (1)
    float* __restrict__ out) {               // (24,512)
  int b0 = blockIdx.x * 16;
  int tid = threadIdx.x, w = tid >> 6, lane = tid & 63, q = lane >> 4, c16 = lane & 15;
  int d = w >> 3, w8 = w & 7;
  __shared__ unsigned short hc0[16 * 264];
  __shared__ unsigned short hc1[16 * 264];
  __shared__ float x0s[16];
  __shared__ float fcwf[256];
  int jj = w8 * 16 + c16;  // h-column within this d
  int jw = w8 * 16;        // wave column base

  const unsigned short* Wd0 = Whh + (size_t)d * 384 * 128;        // layer0 own d
  const unsigned short* Wh1 = Whh + (size_t)(2 + d) * 384 * 128;  // layer1 own d
  const unsigned short* Wi1 = Wih1 + (size_t)d * 384 * 256;

  float hs[2][4];   // [layer][rr] for own (d, 16-col group)
#pragma unroll
  for (int l = 0; l < 2; l++)
#pragma unroll
    for (int rr = 0; rr < 4; rr++) {
      int row = q * 4 + rr;
      int cell = l * 2 + d;
      float v = HS[((size_t)cell * 512 + b0 + row) * 128 + jj];
      hs[l][rr] = v;
      unsigned short bv = f2bf(v);
      unsigned short* tile = l ? hc1 : hc0;
      tile[row * 264 + d * 128 + jj] = bv;
    }
  if (tid < 16) x0s[tid] = x0save[b0 + tid];
  if (tid < 256) fcwf[tid] = fc_w[tid];

  float w0c[3], bi0[3], bh0[3], bi1[3], bh1[3];
#pragma unroll
  for (int g = 0; g < 3; g++) {
    int col = g * 128 + jj;
    w0c[g] = Wih0[d * 384 + col];
    bi0[g] = bih[d * 384 + col];
    bh0[g] = bhh[d * 384 + col];
    bi1[g] = bih[(2 + d) * 384 + col];
    bh1[g] = bhh[(2 + d) * 384 + col];
  }
  __syncthreads();

  for (int st = 0; st < 24; st++) {
    // ---- layer 0 (input = scalar x0), own (d, 16 cols) ----
    float hn0[4];
    {
      short8_t a0[4];
#pragma unroll
      for (int kt = 0; kt < 4; kt++)
        a0[kt] = ld8(&hc0[c16 * 264 + d * 128 + kt * 32 + q * 8]);
      f32x4_t acc[3];
#pragma unroll
      for (int g = 0; g < 3; g++) acc[g] = (f32x4_t){0.f, 0.f, 0.f, 0.f};
#pragma unroll
      for (int kp = 0; kp < 2; kp++) {         // 2-kt batches
        short8_t wb[6];
#pragma unroll
        for (int k2 = 0; k2 < 2; k2++)
#pragma unroll
          for (int g = 0; g < 3; g++)
            wb[k2 * 3 + g] = ld8(Wd0 + (size_t)(g * 128 + jw + c16) * 128 +
                                 (kp * 2 + k2) * 32 + q * 8);
#pragma unroll
        for (int k2 = 0; k2 < 2; k2++)
#pragma unroll
          for (int g = 0; g < 3; g++)
            acc[g] = MFMA16(a0[kp * 2 + k2], wb[k2 * 3 + g], acc[g]);
      }
#pragma unroll
      for (int rr = 0; rr < 4; rr++) {
        float xin = x0s[q * 4 + rr];
        float r = sigm(xin * w0c[0] + bi0[0] + acc[0][rr] + bh0[0]);
        float z = sigm(xin * w0c[1] + bi0[1] + acc[1][rr] + bh0[1]);
        float n = tanh_fast(xin * w0c[2] + bi0[2] + r * (acc[2][rr] + bh0[2]));
        float hv = n + z * (hs[0][rr] - n);
        hn0[rr] = hv;
        hs[0][rr] = hv;
      }
    }
    __syncthreads();
#pragma unroll
    for (int rr = 0; rr < 4; rr++)
      hc0[(q * 4 + rr) * 264 + d * 128 + jj] = f2bf(hn0[rr]);
    __syncthreads();

    // ---- layer 1 (input = hc0 concat), own (d, 16 cols) ----
    float hn1[4];
    {
      f32x4_t aRZ[2], aNi, aNh;
      aRZ[0] = (f32x4_t){0.f, 0.f, 0.f, 0.f};
      aRZ[1] = (f32x4_t){0.f, 0.f, 0.f, 0.f};
      aNi = (f32x4_t){0.f, 0.f, 0.f, 0.f};
      aNh = (f32x4_t){0.f, 0.f, 0.f, 0.f};
      // Wi kt 0..7 in 2-kt batches, ai loaded per-batch (2 frags at a time)
#pragma unroll
      for (int kp = 0; kp < 4; kp++) {
        short8_t aia[2];
#pragma unroll
        for (int k2 = 0; k2 < 2; k2++)
          aia[k2] = ld8(&hc0[c16 * 264 + (kp * 2 + k2) * 32 + q * 8]);
        short8_t wb[6];
#pragma unroll
        for (int k2 = 0; k2 < 2; k2++) {
          int kt = kp * 2 + k2;
          wb[k2 * 3 + 0] = ld8(Wi1 + (size_t)(jw + c16) * 256 + kt * 32 + q * 8);
          wb[k2 * 3 + 1] = ld8(Wi1 + (size_t)(128 + jw + c16) * 256 + kt * 32 + q * 8);
          wb[k2 * 3 + 2] = ld8(Wi1 + (size_t)(256 + jw + c16) * 256 + kt * 32 + q * 8);
        }
#pragma unroll
        for (int k2 = 0; k2 < 2; k2++) {
          aRZ[0] = MFMA16(aia[k2], wb[k2 * 3 + 0], aRZ[0]);
          aRZ[1] = MFMA16(aia[k2], wb[k2 * 3 + 1], aRZ[1]);
          aNi    = MFMA16(aia[k2], wb[k2 * 3 + 2], aNi);
        }
      }
      // Wh kt 0..3 in 2-kt batches
#pragma unroll
      for (int kp = 0; kp < 2; kp++) {
        short8_t aha[2];
#pragma unroll
        for (int k2 = 0; k2 < 2; k2++)
          aha[k2] = ld8(&hc1[c16 * 264 + d * 128 + (kp * 2 + k2) * 32 + q * 8]);
        short8_t wb[6];
#pragma unroll
        for (int k2 = 0; k2 < 2; k2++) {
          int kt = kp * 2 + k2;
          wb[k2 * 3 + 0] = ld8(Wh1 + (size_t)(jw + c16) * 128 + kt * 32 + q * 8);
          wb[k2 * 3 + 1] = ld8(Wh1 + (size_t)(128 + jw + c16) * 128 + kt * 32 + q * 8);
          wb[k2 * 3 + 2] = ld8(Wh1 + (size_t)(256 + jw + c16) * 128 + kt * 32 + q * 8);
        }
#pragma unroll
        for (int k2 = 0; k2 < 2; k2++) {
          aRZ[0] = MFMA16(aha[k2], wb[k2 * 3 + 0], aRZ[0]);
          aRZ[1] = MFMA16(aha[k2], wb[k2 * 3 + 1], aRZ[1]);
          aNh    = MFMA16(aha[k2], wb[k2 * 3 + 2], aNh);
        }
      }
#pragma unroll
      for (int rr = 0; rr < 4; rr++) {
        float r = sigm(aRZ[0][rr] + bi1[0] + bh1[0]);
        float z = sigm(aRZ[1][rr] + bi1[1] + bh1[1]);
        float n = tanh_fast(aNi[rr] + bi1[2] + r * (aNh[rr] + bh1[2]));
        float hv = n + z * (hs[1][rr] - n);
        hn1[rr] = hv;
        hs[1][rr] = hv;
      }
    }
    __syncthreads();
#pragma unroll
    for (int rr = 0; rr < 4; rr++)
      hc1[(q * 4 + rr) * 264 + d * 128 + jj] = f2bf(hn1[rr]);
    __syncthreads();

    // ---- fc -> pred, feed back (wave 0 only) ----
    if (w == 0) {
      float s = 0.f;
#pragma unroll
      for (int i = 0; i < 8; i++) {
        short8_t hv = ld8(&hc1[c16 * 264 + q * 64 + i * 8]);
#pragma unroll
        for (int e = 0; e < 8; e++)
          s += bf2f((unsigned short)hv[e]) * fcwf[q * 64 + i * 8 + e];
      }
      s += __shfl_xor(s, 16);
      s += __shfl_xor(s, 32);
      if (q == 0) {
        float pred = s + fcb[0];
        x0s[c16] = pred;
        out[(size_t)st * 512 + b0 + c16] = pred;
      }
    }
    __syncthreads();
  }
}

// ---------------------------------------------------------------------------
extern "C" void kernel_launch(void* const* d_in, const int* in_sizes, int n_in,
                              void* d_out, int out_size, void* d_ws, size_t ws_size,
                              hipStream_t stream) {
  const float* x     = (const float*)d_in[0];
  const float* eWih0 = (const float*)d_in[1];
  const float* eWih1 = (const float*)d_in[2];
  const float* eWhh  = (const float*)d_in[3];
  const float* ebih  = (const float*)d_in[4];
  const float* ebhh  = (const float*)d_in[5];
  const float* dWih0 = (const float*)d_in[6];
  const float* dWih1 = (const float*)d_in[7];
  const float* dWhh  = (const float*)d_in[8];
  const float* dbih  = (const float*)d_in[9];
  const float* dbhh  = (const float*)d_in[10];
  const float* fc_w  = (const float*)d_in[11];
  const float* fc_b  = (const float*)d_in[12];
  float* out = (float*)d_out;
  (void)in_sizes; (void)n_in; (void)out_size;

  // ---- ws ladder: xc = Bc*131072 bytes (512 t x Bc rows x 64 fp32) --------
  // Bc=512 total 68.95MB == previously-passing budget; else Bc=256 (35.4MB)
  const size_t fixedB = 2048 + 1048576 + 393216 + 393216 + 4096;
  int Bc = 256;
  if (fixedB + (size_t)512 * 131072 <= ws_size) Bc = 512;

  char* ws = (char*)d_ws;
  size_t off = 0;
  auto alloc = [&](size_t bytes) -> char* {
    off = (off + 255) & ~(size_t)255;
    char* p = ws + off;
    off += bytes;
    return p;
  };
  float* x0save          = (float*)alloc(2048);
  float* HS              = (float*)alloc(1048576);
  unsigned short* bdWih1 = (unsigned short*)alloc(393216);   // 196608 elems
  unsigned short* bdWhh  = (unsigned short*)alloc(393216);   // 196608 elems
  float* xc              = (float*)alloc((size_t)Bc * 131072);

  k_prep<<<194, 256, 0, stream>>>(x, dWih1, dWhh, bdWih1, bdWhh, x0save);

  float* xm = (float*)d_in[0];   // mutable view: fwd overlay target
  const float* Whh1 = eWhh + (size_t)2 * 384 * 128;
  int nchunks = 512 / Bc;
  for (int c = 0; c < nchunks; c++) {
    int b_base = c * Bc;
    int ncopy = (512 * Bc * 16 + 255) / 256;
    k_copy<<<ncopy, 256, 0, stream>>>(x, xc, b_base, Bc);
    k_scan0d<<<dim3(Bc / 16, 2), 256, 0, stream>>>(xm, xc, eWih0, ebih, eWhh, ebhh,
                                                   HS, b_base, Bc);
    k_scan1<<<dim3(Bc / 16, 2), 512, 0, stream>>>((const unsigned short*)xm,
                                                  (const unsigned short*)xc,
                                                  eWih1, ebih + 768, Whh1,
                                                  ebhh + 768, HS, b_base, Bc);
  }
  k_dec<<<dim3(32), 1024, 0, stream>>>(x0save, HS, bdWhh, bdWih1, dWih0, dbih, dbhh,
                                       fc_w, fc_b, out);
}

// Round 12
// 1736.175 us; speedup vs baseline: 1.0994x; 1.0112x over previous
//
#include <hip/hip_runtime.h>
#include <cstdint>
#include <cstddef>

// ---------------------------------------------------------------------------
// Seq2Seq bi-GRU encoder (T=512,B=512,D=64,H=128,L=2) + 24-step GRU decoder.
// R20. Scans = R16 verbatim (best: scan1 679, scan0d ~571). Dec = R16 8-wave
// body with ONE change: weight loads read a PRE-SWIZZLED fragment-linear
// copy. Theory: dec's ~47kcy/step is load-transaction-bound -- each old ld8
// (lane (q,c16) -> 16 rows x 64B at 512B stride) fragments into 16 L2
// transactions; 96 loads/wave/step saturate the per-CU miss queue (fits all
// evidence: R13 TLP win then R19 null -- queue is per-CU; R17 pin hurt --
// bursts worsen queueing). k_prep now writes bdWih1/bdWhh in fragment order:
// frag(cg,kt) = 64 lanes x 16B contiguous (1KB); dec loads
// ld8(base + frag*512 + lane*8) = ONE coalesced transaction. Same values,
// same MFMA order -> bit-identical. Same ws sizes. prep reads scattered
// (one-shot, ~+5us). copy/launcher unchanged.
// ---------------------------------------------------------------------------

typedef __attribute__((ext_vector_type(8))) short short8_t;
typedef __attribute__((ext_vector_type(4))) short short4_t;
typedef __attribute__((ext_vector_type(4))) float f32x4_t;

#define MFMA16(a, b, c) __builtin_amdgcn_mfma_f32_16x16x32_bf16((a), (b), (c), 0, 0, 0)

// raw barrier: LDS flush only; vmem (global loads/stores) stay in flight
#define BAR_LDS() asm volatile("s_waitcnt lgkmcnt(0)\n\ts_barrier" ::: "memory")

static __device__ __forceinline__ float bf2f(unsigned short u) {
  unsigned int v = ((unsigned int)u) << 16;
  return __builtin_bit_cast(float, v);
}
static __device__ __forceinline__ unsigned short f2bf(float f) {
  unsigned int x = __builtin_bit_cast(unsigned int, f);
  x += 0x7fffu + ((x >> 16) & 1u);   // round-to-nearest-even
  return (unsigned short)(x >> 16);
}
static __device__ __forceinline__ short8_t ld8(const unsigned short* p) {
  return *reinterpret_cast<const short8_t*>(p);
}
static __device__ __forceinline__ f32x4_t ldf4(const float* p) {
  return *reinterpret_cast<const f32x4_t*>(p);
}
static __device__ __forceinline__ short8_t cvt8f(const float* p) {
  const f32x4_t* v = reinterpret_cast<const f32x4_t*>(p);
  f32x4_t a = v[0], b = v[1];
  short8_t r;
  r[0] = (short)f2bf(a[0]); r[1] = (short)f2bf(a[1]);
  r[2] = (short)f2bf(a[2]); r[3] = (short)f2bf(a[3]);
  r[4] = (short)f2bf(b[0]); r[5] = (short)f2bf(b[1]);
  r[6] = (short)f2bf(b[2]); r[7] = (short)f2bf(b[3]);
  return r;
}
static __device__ __forceinline__ float frcp(float x) {
  return __builtin_amdgcn_rcpf(x);               // v_rcp_f32, <=1ulp
}
static __device__ __forceinline__ float sigm(float x) {
  return frcp(1.0f + __expf(-x));
}
static __device__ __forceinline__ float tanh_fast(float y) {
  float t = __expf(-2.0f * fabsf(y));
  float r = (1.0f - t) * frcp(1.0f + t);
  return copysignf(r, y);
}

// ------------- prep: swizzle-cast decoder weights, snapshot x[-1,:,0] -------
// bdWih1: per d (2): frag f = cg*8 + kt (cg 0..23, kt 0..7), 64 lanes x 8
//   shorts: elem (lane,e) = Wih1[d][cg*16 + (lane&15)][kt*32 + (lane>>4)*8 + e]
// bdWhh: per cell cd (4 = layer*2+d): frag f = cg*4 + kt (cg 0..23, kt 0..3)
//   elem (lane,e) = Whh[cd][cg*16 + (lane&15)][kt*32 + (lane>>4)*8 + e]
__global__ void k_prep(const float* __restrict__ x,
                       const float* __restrict__ dWih1, const float* __restrict__ dWhh,
                       unsigned short* __restrict__ bdWih1, unsigned short* __restrict__ bdWhh,
                       float* __restrict__ x0save) {
  const int NW = 24576;   // 196608 elems / 8
  int i = blockIdx.x * blockDim.x + threadIdx.x;
  if (i < NW) {
    int d = i / 12288, r = i - d * 12288;      // 12288 = 192 frags * 64 lanes
    int f = r >> 6, lane = r & 63;
    int cg = f >> 3, kt = f & 7;
    int n = cg * 16 + (lane & 15);
    int cb = kt * 32 + (lane >> 4) * 8;
    *reinterpret_cast<short8_t*>(bdWih1 + (size_t)i * 8) =
        cvt8f(dWih1 + ((size_t)d * 384 + n) * 256 + cb);
  } else if (i < 2 * NW) {
    int j = i - NW;
    int cd = j / 6144, r = j - cd * 6144;      // 6144 = 96 frags * 64 lanes
    int f = r >> 6, lane = r & 63;
    int cg = f >> 2, kt = f & 3;
    int n = cg * 16 + (lane & 15);
    int cb = kt * 32 + (lane >> 4) * 8;
    *reinterpret_cast<short8_t*>(bdWhh + (size_t)j * 8) =
        cvt8f(dWhh + ((size_t)cd * 384 + n) * 128 + cb);
  } else if (i < 2 * NW + 512) {
    int b = i - 2 * NW;
    x0save[b] = x[((size_t)511 * 512 + b) * 64];
  }
}

// ------------- copy chunk of x into ws (bwd's private read+overlay buffer) --
__global__ void k_copy(const float* __restrict__ x, float* __restrict__ xc,
                       int b_base, int Bc) {
  size_t i = (size_t)blockIdx.x * blockDim.x + threadIdx.x;
  size_t per = (size_t)Bc * 16;            // float4s per t-slab
  size_t n = (size_t)512 * per;
  if (i >= n) return;
  size_t t = i / per, r = i - t * per;
  const f32x4_t* s =
      reinterpret_cast<const f32x4_t*>(x + ((size_t)t * 512 + b_base) * 64) + r;
  f32x4_t* d = reinterpret_cast<f32x4_t*>(xc + t * per * 4) + r;
  *d = *s;
}

// ---- layer-0 scan, one dir per block (blockIdx.y), gi fused (K=64) ---------
// grid (Bc/16, 2). Block = 16 batch rows, 4 waves; wave w owns h-cols
// [w*32,+32). One-step-ahead gi (R16): step s computes gx(s+1) off-path,
// gates use gx(s) from registers. Serial path = hl round trip + h-MFMAs.
__global__ __launch_bounds__(256, 1) void k_scan0d(
    float* x,                               // (512,512,64) fp32; fwd in+out
    float* xc,                              // (512,Bc,64) fp32 copy; bwd in+out
    const float* __restrict__ Wih,          // enc_Wih0 (2,384,64) fp32
    const float* __restrict__ bih,          // (2,384) layer0
    const float* __restrict__ Whh,          // (2,384,128) layer0
    const float* __restrict__ bhh,          // (2,384) layer0
    float* __restrict__ HS,                 // (4,512,128) fp32
    int b_base, int Bc) {
  int dir = blockIdx.y;
  int bl0 = blockIdx.x * 16;                // chunk-local batch base
  int b0g = b_base + bl0;                   // global batch base
  float* xin = dir ? xc : x;                // private read+overlay buffer
  unsigned short* yout = (unsigned short*)xin;
  int xstr = dir ? Bc : 512;                // row stride in that buffer
  int xb0 = dir ? bl0 : b0g;                // row base in that buffer
  int tid = threadIdx.x, w = tid >> 6, lane = tid & 63, q = lane >> 4, c16 = lane & 15;
  __shared__ unsigned short xl[2][16 * 72];    // x tile bf16 (+8 pad)
  __shared__ unsigned short hl[2][16 * 136];   // h tile bf16 (+8 pad)
  const float* Wi = Wih + (size_t)dir * 384 * 64;
  const float* Wh = Whh + (size_t)dir * 384 * 128;
  const float* bi = bih + dir * 384;
  const float* bh = bhh + dir * 384;

  short8_t fi[6][2], fh[6][4];
  float brz[4], bni[2], bnh[2];
#pragma unroll
  for (int g = 0; g < 3; g++)
#pragma unroll
    for (int cc = 0; cc < 2; cc++) {
      int f = g * 2 + cc;
      int n0 = g * 128 + w * 32 + cc * 16;
#pragma unroll
      for (int kt = 0; kt < 2; kt++)
        fi[f][kt] = cvt8f(Wi + (size_t)(n0 + c16) * 64 + kt * 32 + q * 8);
#pragma unroll
      for (int kt = 0; kt < 4; kt++)
        fh[f][kt] = cvt8f(Wh + (size_t)(n0 + c16) * 128 + kt * 32 + q * 8);
      if (g < 2) brz[f] = bi[n0 + c16] + bh[n0 + c16];
      else { bni[cc] = bi[n0 + c16]; bnh[cc] = bh[n0 + c16]; }
    }

  float h[2][4];
#pragma unroll
  for (int cc = 0; cc < 2; cc++)
#pragma unroll
    for (int rr = 0; rr < 4; rr++) h[cc][rr] = 0.f;
  for (int i = tid; i < 16 * 136; i += 256) hl[0][i] = 0;

  int srow = tid >> 4, sc = tid & 15;          // staging/writeback roles
#pragma unroll
  for (int k = 0; k < 2; k++) {                // stage x tiles for steps 0,1
    int tk = dir ? (511 - k) : k;
    f32x4_t v = ldf4(xin + ((size_t)tk * xstr + xb0 + srow) * 64 + sc * 4);
    unsigned short* dst = &xl[k][srow * 72 + sc * 4];
    dst[0] = f2bf(v[0]); dst[1] = f2bf(v[1]); dst[2] = f2bf(v[2]); dst[3] = f2bf(v[3]);
  }
  f32x4_t pA, pB;                              // prefetch regs (x(s+2) held)
  {                                            // pA <- x(step 2)
    int t2 = dir ? 509 : 2;
    pA = ldf4(xin + ((size_t)t2 * xstr + xb0 + srow) * 64 + sc * 4);
  }
  __syncthreads();                             // prologue: full drain once

  // gx(0) from xl[0] (gx layout: [0..3]=RZ by f, [4..5]=Ni by cc)
  f32x4_t gxA[6], gxB[6];
#pragma unroll
  for (int f = 0; f < 6; f++) gxA[f] = (f32x4_t){0.f, 0.f, 0.f, 0.f};
#pragma unroll
  for (int kt = 0; kt < 2; kt++) {
    short8_t ax = ld8(&xl[0][c16 * 72 + kt * 32 + q * 8]);
#pragma unroll
    for (int f = 0; f < 4; f++) gxA[f] = MFMA16(ax, fi[f][kt], gxA[f]);
#pragma unroll
    for (int cc = 0; cc < 2; cc++) gxA[4 + cc] = MFMA16(ax, fi[4 + cc][kt], gxA[4 + cc]);
  }
  BAR_LDS();                                   // protect xl[0] reads from body(0)'s commit

  auto body = [&](int s, f32x4_t (&gxC)[6], f32x4_t (&gxN)[6],
                  const f32x4_t& xu, f32x4_t& xnl) {
    int cur = s & 1, nxt = cur ^ 1;            // hl slots; xl: rd=nxt, wr=cur
    if (s < 509) {                             // issue load for x(s+3)
      int tn = dir ? (508 - s) : (s + 3);
      xnl = ldf4(xin + ((size_t)tn * xstr + xb0 + srow) * 64 + sc * 4);
    }
    if (s < 510) {                             // commit x(s+2) into xl[cur]
      unsigned short* dst = &xl[cur][srow * 72 + sc * 4];
      dst[0] = f2bf(xu[0]); dst[1] = f2bf(xu[1]); dst[2] = f2bf(xu[2]); dst[3] = f2bf(xu[3]);
    }
    if (s > 0) {                               // Yout for h(s-1), held in hl[cur]
      int tp = dir ? (512 - s) : (s - 1);
      short8_t v = ld8(&hl[cur][srow * 136 + sc * 8]);
      *reinterpret_cast<short8_t*>(
          yout + ((size_t)tp * xstr + xb0 + srow) * 128 + sc * 8) = v;
    }
    // ---- serial h-part ----
    short8_t ah[4];
#pragma unroll
    for (int kt = 0; kt < 4; kt++) ah[kt] = ld8(&hl[cur][c16 * 136 + kt * 32 + q * 8]);
    f32x4_t aRZh[4], aNh[2];
#pragma unroll
    for (int f = 0; f < 4; f++) aRZh[f] = (f32x4_t){0.f, 0.f, 0.f, 0.f};
#pragma unroll
    for (int cc = 0; cc < 2; cc++) aNh[cc] = (f32x4_t){0.f, 0.f, 0.f, 0.f};
#pragma unroll
    for (int kt = 0; kt < 4; kt++) {
#pragma unroll
      for (int f = 0; f < 4; f++) aRZh[f] = MFMA16(ah[kt], fh[f][kt], aRZh[f]);
#pragma unroll
      for (int cc = 0; cc < 2; cc++) aNh[cc] = MFMA16(ah[kt], fh[4 + cc][kt], aNh[cc]);
    }
    // ---- off-path: gx(s+1) from xl[nxt] ----
    if (s < 511) {
#pragma unroll
      for (int f = 0; f < 6; f++) gxN[f] = (f32x4_t){0.f, 0.f, 0.f, 0.f};
#pragma unroll
      for (int kt = 0; kt < 2; kt++) {
        short8_t ax = ld8(&xl[nxt][c16 * 72 + kt * 32 + q * 8]);
#pragma unroll
        for (int f = 0; f < 4; f++) gxN[f] = MFMA16(ax, fi[f][kt], gxN[f]);
#pragma unroll
        for (int cc = 0; cc < 2; cc++) gxN[4 + cc] = MFMA16(ax, fi[4 + cc][kt], gxN[4 + cc]);
      }
    }
    // ---- gates (use gx(s) = gxC) ----
#pragma unroll
    for (int cc = 0; cc < 2; cc++)
#pragma unroll
      for (int rr = 0; rr < 4; rr++) {
        float r = sigm(gxC[cc][rr] + aRZh[cc][rr] + brz[cc]);
        float z = sigm(gxC[2 + cc][rr] + aRZh[2 + cc][rr] + brz[2 + cc]);
        float n = tanh_fast(gxC[4 + cc][rr] + bni[cc] + r * (aNh[cc][rr] + bnh[cc]));
        float hn = n + z * (h[cc][rr] - n);
        h[cc][rr] = hn;
        hl[nxt][(q * 4 + rr) * 136 + w * 32 + c16 + cc * 16] = f2bf(hn);
      }
    BAR_LDS();
  };

  for (int s2 = 0; s2 < 256; s2++) {
    body(2 * s2, gxA, gxB, pA, pB);
    body(2 * s2 + 1, gxB, gxA, pB, pA);
  }
  {                                            // final Yout row (step 511's h in hl[0])
    int tp = dir ? 0 : 511;
    short8_t v = ld8(&hl[0][srow * 136 + sc * 8]);
    *reinterpret_cast<short8_t*>(
        yout + ((size_t)tp * xstr + xb0 + srow) * 128 + sc * 8) = v;
  }
#pragma unroll
  for (int cc = 0; cc < 2; cc++)
#pragma unroll
    for (int rr = 0; rr < 4; rr++)
      HS[((size_t)dir * 512 + b0g + q * 4 + rr) * 128 + w * 32 + c16 + cc * 16] = h[cc][rr];
}

// ---- layer-1 scan, gi fused (K=256 = [OutF||OutB]), both dirs --------------
// grid (Bc/16, 2). Block = 512 thr (8 waves); wave w owns h-cols [w*16,+16).
// One-step-ahead gi (R16): step s computes gi(s+1) off-path; gates use gi(s).
__global__ __launch_bounds__(512, 1) void k_scan1(
    const unsigned short* __restrict__ OutF,  // x overlay
    const unsigned short* __restrict__ OutB,  // xc overlay
    const float* __restrict__ Wih1,           // enc_Wih1 (2,384,256) fp32
    const float* __restrict__ bih1,           // (2,384) layer1
    const float* __restrict__ Whh1,           // (2,384,128) layer1
    const float* __restrict__ bhh1,           // (2,384) layer1
    float* __restrict__ HS,
    int b_base, int Bc) {
  int dir = blockIdx.y;
  int b0l = blockIdx.x * 16;
  int tid = threadIdx.x, w = tid >> 6, lane = tid & 63, q = lane >> 4, c16 = lane & 15;
  __shared__ unsigned short il[2][16 * 264];   // input tile (256 + 8 pad)
  __shared__ unsigned short hl[2][16 * 136];
  const float* Wi = Wih1 + (size_t)dir * 384 * 256;
  const float* Wh = Whh1 + (size_t)dir * 384 * 128;
  const float* bi = bih1 + dir * 384;
  const float* bh = bhh1 + dir * 384;

  short8_t fi[3][8], fh[3][4];
  float brz[2], bni, bnh;
#pragma unroll
  for (int g = 0; g < 3; g++) {
    int n0 = g * 128 + w * 16;
#pragma unroll
    for (int kt = 0; kt < 8; kt++)
      fi[g][kt] = cvt8f(Wi + (size_t)(n0 + c16) * 256 + kt * 32 + q * 8);
#pragma unroll
    for (int kt = 0; kt < 4; kt++)
      fh[g][kt] = cvt8f(Wh + (size_t)(n0 + c16) * 128 + kt * 32 + q * 8);
    if (g < 2) brz[g] = bi[n0 + c16] + bh[n0 + c16];
    else { bni = bi[n0 + c16]; bnh = bh[n0 + c16]; }
  }

  float h[4] = {0.f, 0.f, 0.f, 0.f};
  for (int i = tid; i < 16 * 136; i += 512) hl[0][i] = 0;

  int srow = tid >> 5, sc = tid & 31;          // staging: 16 rows x 32 col-chunks
#pragma unroll
  for (int k = 0; k < 2; k++) {                // stage il for steps 0,1
    int tk = dir ? (511 - k) : k;
    short8_t v = (sc < 16)
        ? ld8(OutF + ((size_t)tk * 512 + b_base + b0l + srow) * 128 + sc * 8)
        : ld8(OutB + ((size_t)tk * Bc + b0l + srow) * 128 + (sc - 16) * 8);
    *reinterpret_cast<short8_t*>(&il[k][srow * 264 + sc * 8]) = v;
  }
  short8_t ivA, ivB;                           // prefetch regs (il(s+2) held)
  {                                            // ivA <- il(step 2)
    int t2 = dir ? 509 : 2;
    ivA = (sc < 16)
        ? ld8(OutF + ((size_t)t2 * 512 + b_base + b0l + srow) * 128 + sc * 8)
        : ld8(OutB + ((size_t)t2 * Bc + b0l + srow) * 128 + (sc - 16) * 8);
  }
  __syncthreads();                             // prologue: full drain once

  // gi(0) from il[0] (single 8-deep chain per g — R14 arithmetic)
  f32x4_t giA[3], giB[3];
#pragma unroll
  for (int g = 0; g < 3; g++) giA[g] = (f32x4_t){0.f, 0.f, 0.f, 0.f};
#pragma unroll
  for (int kt = 0; kt < 8; kt++) {
    short8_t a = ld8(&il[0][c16 * 264 + kt * 32 + q * 8]);
#pragma unroll
    for (int g = 0; g < 3; g++) giA[g] = MFMA16(a, fi[g][kt], giA[g]);
  }
  BAR_LDS();                                   // protect il[0] reads from body(0)'s commit

  auto body = [&](int s, f32x4_t (&giC)[3], f32x4_t (&giN)[3],
                  const short8_t& iu, short8_t& inl) {
    int cur = s & 1, nxt = cur ^ 1;            // hl slots; il: rd=nxt, wr=cur
    if (s < 509) {                             // issue load for il(s+3)
      int tn = dir ? (508 - s) : (s + 3);
      inl = (sc < 16)
          ? ld8(OutF + ((size_t)tn * 512 + b_base + b0l + srow) * 128 + sc * 8)
          : ld8(OutB + ((size_t)tn * Bc + b0l + srow) * 128 + (sc - 16) * 8);
    }
    if (s < 510)                               // commit il(s+2) into il[cur]
      *reinterpret_cast<short8_t*>(&il[cur][srow * 264 + sc * 8]) = iu;
    // ---- serial h-part ----
    f32x4_t aH[3];
#pragma unroll
    for (int g = 0; g < 3; g++) aH[g] = (f32x4_t){0.f, 0.f, 0.f, 0.f};
#pragma unroll
    for (int kt = 0; kt < 4; kt++) {
      short8_t a = ld8(&hl[cur][c16 * 136 + kt * 32 + q * 8]);
#pragma unroll
      for (int g = 0; g < 3; g++) aH[g] = MFMA16(a, fh[g][kt], aH[g]);
    }
    // ---- off-path: gi(s+1) from il[nxt] ----
    if (s < 511) {
#pragma unroll
      for (int g = 0; g < 3; g++) giN[g] = (f32x4_t){0.f, 0.f, 0.f, 0.f};
#pragma unroll
      for (int kt = 0; kt < 8; kt++) {
        short8_t a = ld8(&il[nxt][c16 * 264 + kt * 32 + q * 8]);
#pragma unroll
        for (int g = 0; g < 3; g++) giN[g] = MFMA16(a, fi[g][kt], giN[g]);
      }
    }
    // ---- gates (use gi(s) = giC) ----
#pragma unroll
    for (int rr = 0; rr < 4; rr++) {
      float r = sigm(giC[0][rr] + aH[0][rr] + brz[0]);
      float z = sigm(giC[1][rr] + aH[1][rr] + brz[1]);
      float n = tanh_fast(giC[2][rr] + bni + r * (aH[2][rr] + bnh));
      float hn = n + z * (h[rr] - n);
      h[rr] = hn;
      hl[nxt][(q * 4 + rr) * 136 + w * 16 + c16] = f2bf(hn);
    }
    BAR_LDS();
  };

  for (int s2 = 0; s2 < 256; s2++) {
    body(2 * s2, giA, giB, ivA, ivB);
    body(2 * s2 + 1, giB, giA, ivB, ivA);
  }
#pragma unroll
  for (int rr = 0; rr < 4; rr++)
    HS[((size_t)(2 + dir) * 512 + b_base + b0l + q * 4 + rr) * 128 + w * 16 + c16] = h[rr];
}

// ------------------------------- decoder (R16 8-wave + swizzled weights) ----
// d-cells split across wave groups. 512 thr = 8 waves; d = w>>2, w4 = w&3
// owns cols [w4*32,+32) of its d. Weight loads are fragment-linear:
// ld8(base + frag*512 + lane*8) = one coalesced 1KB transaction (was a
// 16-transaction scatter). Frag indices: Whh cell cd: f = cg*4 + kt;
// Wih1 d: f = cg*8 + kt; cg = gate_block*8 + w4*2 + cc (gate_block: r=0,z=1,
// n=2). MFMA order per accumulator preserved -> bit-identical.
__global__ __launch_bounds__(512, 1) void k_dec(
    const float* __restrict__ x0save,        // (512)
    const float* __restrict__ HS,            // (4,512,128) = [l0f,l0b,l1f,l1b]
    const unsigned short* __restrict__ Whh,  // dec swizzled (4 cells x 96 frags)
    const unsigned short* __restrict__ Wih1, // dec swizzled (2 d x 192 frags)
    const float* __restrict__ Wih0,          // dec (2,384,1) fp32
    const float* __restrict__ bih,           // (2,2,384)
    const float* __restrict__ bhh,           // (2,2,384)
    const float* __restrict__ fc_w,          // (256) fp32
    const float* __restrict__ fcb,           // (1)
    float* __restrict__ out) {               // (24,512)
  int b0 = blockIdx.x * 16;
  int tid = threadIdx.x, w = tid >> 6, lane = tid & 63, q = lane >> 4, c16 = lane & 15;
  int d = w >> 2, w4 = w & 3;
  __shared__ unsigned short hc0[16 * 264];
  __shared__ unsigned short hc1[16 * 264];
  __shared__ float x0s[16];
  __shared__ float fcwf[256];
  int jj = w4 * 32 + c16;  // h-column within this d (biases, LDS addressing)
  int cgb = w4 * 2;        // colgroup base within each 128-col gate block

  const unsigned short* Wd0 = Whh + (size_t)d * 49152;        // layer0 own d
  const unsigned short* Wh1 = Whh + (size_t)(2 + d) * 49152;  // layer1 own d
  const unsigned short* Wi1 = Wih1 + (size_t)d * 98304;

  float hs[2][2][4];   // [layer][cc][rr] for own d
#pragma unroll
  for (int l = 0; l < 2; l++)
#pragma unroll
    for (int cc = 0; cc < 2; cc++)
#pragma unroll
      for (int rr = 0; rr < 4; rr++) {
        int row = q * 4 + rr, j = jj + cc * 16;
        int cell = l * 2 + d;
        float v = HS[((size_t)cell * 512 + b0 + row) * 128 + j];
        hs[l][cc][rr] = v;
        unsigned short bv = f2bf(v);
        unsigned short* tile = l ? hc1 : hc0;
        tile[row * 264 + d * 128 + j] = bv;
      }
  if (tid < 16) x0s[tid] = x0save[b0 + tid];
  if (tid < 256) fcwf[tid] = fc_w[tid];

  float w0c[2][3], bi0[2][3], bh0[2][3], bi1[2][3], bh1[2][3];
#pragma unroll
  for (int cc = 0; cc < 2; cc++)
#pragma unroll
    for (int g = 0; g < 3; g++) {
      int col = g * 128 + jj + cc * 16;
      w0c[cc][g] = Wih0[d * 384 + col];
      bi0[cc][g] = bih[d * 384 + col];
      bh0[cc][g] = bhh[d * 384 + col];
      bi1[cc][g] = bih[(2 + d) * 384 + col];
      bh1[cc][g] = bhh[(2 + d) * 384 + col];
    }
  __syncthreads();

  for (int st = 0; st < 24; st++) {
    // ---- layer 0 (input = scalar x0), own d only ----
    float hn0[2][4];
    {
      short8_t a0[4];
#pragma unroll
      for (int kt = 0; kt < 4; kt++)
        a0[kt] = ld8(&hc0[c16 * 264 + d * 128 + kt * 32 + q * 8]);
      short8_t w0[24];                         // batch 24 coalesced loads
#pragma unroll
      for (int kt = 0; kt < 4; kt++)
#pragma unroll
        for (int g = 0; g < 3; g++)
#pragma unroll
          for (int cc = 0; cc < 2; cc++) {
            int cg = g * 8 + cgb + cc;
            w0[kt * 6 + g * 2 + cc] = ld8(Wd0 + (size_t)(cg * 4 + kt) * 512 + lane * 8);
          }
      f32x4_t acc[6];
#pragma unroll
      for (int f = 0; f < 6; f++) acc[f] = (f32x4_t){0.f, 0.f, 0.f, 0.f};
#pragma unroll
      for (int kt = 0; kt < 4; kt++)
#pragma unroll
        for (int g = 0; g < 3; g++)
#pragma unroll
          for (int cc = 0; cc < 2; cc++) {
            int f = g * 2 + cc;
            acc[f] = MFMA16(a0[kt], w0[kt * 6 + g * 2 + cc], acc[f]);
          }
#pragma unroll
      for (int cc = 0; cc < 2; cc++)
#pragma unroll
        for (int rr = 0; rr < 4; rr++) {
          float xin = x0s[q * 4 + rr];
          float r = sigm(xin * w0c[cc][0] + bi0[cc][0] + acc[cc][rr] + bh0[cc][0]);
          float z = sigm(xin * w0c[cc][1] + bi0[cc][1] + acc[2 + cc][rr] + bh0[cc][1]);
          float n = tanh_fast(xin * w0c[cc][2] + bi0[cc][2] +
                              r * (acc[4 + cc][rr] + bh0[cc][2]));
          float hv = n + z * (hs[0][cc][rr] - n);
          hn0[cc][rr] = hv;
          hs[0][cc][rr] = hv;
        }
    }
    __syncthreads();
#pragma unroll
    for (int cc = 0; cc < 2; cc++)
#pragma unroll
      for (int rr = 0; rr < 4; rr++)
        hc0[(q * 4 + rr) * 264 + d * 128 + jj + cc * 16] = f2bf(hn0[cc][rr]);
    __syncthreads();

    // ---- layer 1 (input = hc0 concat), own d only ----
    float hn1[2][4];
    {
      short8_t ai[8];
#pragma unroll
      for (int kt = 0; kt < 8; kt++) ai[kt] = ld8(&hc0[c16 * 264 + kt * 32 + q * 8]);
      short8_t ah[4];
#pragma unroll
      for (int kt = 0; kt < 4; kt++)
        ah[kt] = ld8(&hc1[c16 * 264 + d * 128 + kt * 32 + q * 8]);
      f32x4_t aRZ[4], aNi[2], aNh[2];
#pragma unroll
      for (int f = 0; f < 4; f++) aRZ[f] = (f32x4_t){0.f, 0.f, 0.f, 0.f};
#pragma unroll
      for (int cc = 0; cc < 2; cc++) {
        aNi[cc] = (f32x4_t){0.f, 0.f, 0.f, 0.f};
        aNh[cc] = (f32x4_t){0.f, 0.f, 0.f, 0.f};
      }
      {                                        // batch A: Wi kt 0..3
        short8_t wA[24];
#pragma unroll
        for (int kt = 0; kt < 4; kt++) {
#pragma unroll
          for (int f = 0; f < 4; f++) {
            int cg = (f >> 1) * 8 + cgb + (f & 1);
            wA[kt * 6 + f] = ld8(Wi1 + (size_t)(cg * 8 + kt) * 512 + lane * 8);
          }
#pragma unroll
          for (int cc = 0; cc < 2; cc++) {
            int cg = 16 + cgb + cc;
            wA[kt * 6 + 4 + cc] = ld8(Wi1 + (size_t)(cg * 8 + kt) * 512 + lane * 8);
          }
        }
#pragma unroll
        for (int kt = 0; kt < 4; kt++) {
#pragma unroll
          for (int f = 0; f < 4; f++) aRZ[f] = MFMA16(ai[kt], wA[kt * 6 + f], aRZ[f]);
#pragma unroll
          for (int cc = 0; cc < 2; cc++) aNi[cc] = MFMA16(ai[kt], wA[kt * 6 + 4 + cc], aNi[cc]);
        }
      }
      {                                        // batch B: Wi kt 4..7
        short8_t wB[24];
#pragma unroll
        for (int kt = 0; kt < 4; kt++) {
#pragma unroll
          for (int f = 0; f < 4; f++) {
            int cg = (f >> 1) * 8 + cgb + (f & 1);
            wB[kt * 6 + f] = ld8(Wi1 + (size_t)(cg * 8 + kt + 4) * 512 + lane * 8);
          }
#pragma unroll
          for (int cc = 0; cc < 2; cc++) {
            int cg = 16 + cgb + cc;
            wB[kt * 6 + 4 + cc] = ld8(Wi1 + (size_t)(cg * 8 + kt + 4) * 512 + lane * 8);
          }
        }
#pragma unroll
        for (int kt = 0; kt < 4; kt++) {
#pragma unroll
          for (int f = 0; f < 4; f++) aRZ[f] = MFMA16(ai[4 + kt], wB[kt * 6 + f], aRZ[f]);
#pragma unroll
          for (int cc = 0; cc < 2; cc++) aNi[cc] = MFMA16(ai[4 + kt], wB[kt * 6 + 4 + cc], aNi[cc]);
        }
      }
      {                                        // batch H: Wh kt 0..3
        short8_t wH[24];
#pragma unroll
        for (int kt = 0; kt < 4; kt++) {
#pragma unroll
          for (int f = 0; f < 4; f++) {
            int cg = (f >> 1) * 8 + cgb + (f & 1);
            wH[kt * 6 + f] = ld8(Wh1 + (size_t)(cg * 4 + kt) * 512 + lane * 8);
          }
#pragma unroll
          for (int cc = 0; cc < 2; cc++) {
            int cg = 16 + cgb + cc;
            wH[kt * 6 + 4 + cc] = ld8(Wh1 + (size_t)(cg * 4 + kt) * 512 + lane * 8);
          }
        }
#pragma unroll
        for (int kt = 0; kt < 4; kt++) {
#pragma unroll
          for (int f = 0; f < 4; f++) aRZ[f] = MFMA16(ah[kt], wH[kt * 6 + f], aRZ[f]);
#pragma unroll
          for (int cc = 0; cc < 2; cc++) aNh[cc] = MFMA16(ah[kt], wH[kt * 6 + 4 + cc], aNh[cc]);
        }
      }
#pragma unroll
      for (int cc = 0; cc < 2; cc++)
#pragma unroll
        for (int rr = 0; rr < 4; rr++) {
          float r = sigm(aRZ[cc][rr] + bi1[cc][0] + bh1[cc][0]);
          float z = sigm(aRZ[2 + cc][rr] + bi1[cc][1] + bh1[cc][1]);
          float n = tanh_fast(aNi[cc][rr] + bi1[cc][2] + r * (aNh[cc][rr] + bh1[cc][2]));
          float hv = n + z * (hs[1][cc][rr] - n);
          hn1[cc][rr] = hv;
          hs[1][cc][rr] = hv;
        }
    }
    __syncthreads();
#pragma unroll
    for (int cc = 0; cc < 2; cc++)
#pragma unroll
      for (int rr = 0; rr < 4; rr++)
        hc1[(q * 4 + rr) * 264 + d * 128 + jj + cc * 16] = f2bf(hn1[cc][rr]);
    __syncthreads();

    // ---- fc -> pred, feed back (wave 0 only) ----
    if (w == 0) {
      float s = 0.f;
#pragma unroll
      for (int i = 0; i < 8; i++) {
        short8_t hv = ld8(&hc1[c16 * 264 + q * 64 + i * 8]);
#pragma unroll
        for (int e = 0; e < 8; e++)
          s += bf2f((unsigned short)hv[e]) * fcwf[q * 64 + i * 8 + e];
      }
      s += __shfl_xor(s, 16);
      s += __shfl_xor(s, 32);
      if (q == 0) {
        float pred = s + fcb[0];
        x0s[c16] = pred;
        out[(size_t)st * 512 + b0 + c16] = pred;
      }
    }
    __syncthreads();
  }
}

// ---------------------------------------------------------------------------
extern "C" void kernel_launch(void* const* d_in, const int* in_sizes, int n_in,
                              void* d_out, int out_size, void* d_ws, size_t ws_size,
                              hipStream_t stream) {
  const float* x     = (const float*)d_in[0];
  const float* eWih0 = (const float*)d_in[1];
  const float* eWih1 = (const float*)d_in[2];
  const float* eWhh  = (const float*)d_in[3];
  const float* ebih  = (const float*)d_in[4];
  const float* ebhh  = (const float*)d_in[5];
  const float* dWih0 = (const float*)d_in[6];
  const float* dWih1 = (const float*)d_in[7];
  const float* dWhh  = (const float*)d_in[8];
  const float* dbih  = (const float*)d_in[9];
  const float* dbhh  = (const float*)d_in[10];
  const float* fc_w  = (const float*)d_in[11];
  const float* fc_b  = (const float*)d_in[12];
  float* out = (float*)d_out;
  (void)in_sizes; (void)n_in; (void)out_size;

  // ---- ws ladder: xc = Bc*131072 bytes (512 t x Bc rows x 64 fp32) --------
  // Bc=512 total 68.95MB == previously-passing budget; else Bc=256 (35.4MB)
  const size_t fixedB = 2048 + 1048576 + 393216 + 393216 + 4096;
  int Bc = 256;
  if (fixedB + (size_t)512 * 131072 <= ws_size) Bc = 512;

  char* ws = (char*)d_ws;
  size_t off = 0;
  auto alloc = [&](size_t bytes) -> char* {
    off = (off + 255) & ~(size_t)255;
    char* p = ws + off;
    off += bytes;
    return p;
  };
  float* x0save          = (float*)alloc(2048);
  float* HS              = (float*)alloc(1048576);
  unsigned short* bdWih1 = (unsigned short*)alloc(393216);   // 196608 elems (swizzled)
  unsigned short* bdWhh  = (unsigned short*)alloc(393216);   // 196608 elems (swizzled)
  float* xc              = (float*)alloc((size_t)Bc * 131072);

  k_prep<<<194, 256, 0, stream>>>(x, dWih1, dWhh, bdWih1, bdWhh, x0save);

  float* xm = (float*)d_in[0];   // mutable view: fwd overlay target
  const float* Whh1 = eWhh + (size_t)2 * 384 * 128;
  int nchunks = 512 / Bc;
  for (int c = 0; c < nchunks; c++) {
    int b_base = c * Bc;
    int ncopy = (512 * Bc * 16 + 255) / 256;
    k_copy<<<ncopy, 256, 0, stream>>>(x, xc, b_base, Bc);
    k_scan0d<<<dim3(Bc / 16, 2), 256, 0, stream>>>(xm, xc, eWih0, ebih, eWhh, ebhh,
                                                   HS, b_base, Bc);
    k_scan1<<<dim3(Bc / 16, 2), 512, 0, stream>>>((const unsigned short*)xm,
                                                  (const unsigned short*)xc,
                                                  eWih1, ebih + 768, Whh1,
                                                  ebhh + 768, HS, b_base, Bc);
  }
  k_dec<<<dim3(32), 512, 0, stream>>>(x0save, HS, bdWhh, bdWih1, dWih0, dbih, dbhh,
                                      fc_w, fc_b, out);
}